// Round 17
// baseline (275.851 us; speedup 1.0000x reference)
//
#include <hip/hip_runtime.h>
#include <math.h>

#define NB 2
#define NCH 48
#define P 13824        // 24^3
#define DI 96
#define NSTATE 16
#define L 13824
#define CHUNK 32
#define NCK 432        // L / CHUNK
#define TL 32          // rows per fused-xproj block

__device__ __forceinline__ float siluf(float x) { return x / (1.f + __expf(-x)); }
__device__ __forceinline__ float softplusf(float x) {
    return x > 0.f ? x + log1pf(expf(-x)) : log1pf(expf(x));
}

// ---------------- K0: weight reshuffles ----------------
// W2 [48o][48c][27t] -> Wt [4og][27t][48c][12oi]
__global__ __launch_bounds__(256) void k_wtrans(const float* __restrict__ W2,
    const float* __restrict__ W1, const float* __restrict__ W3,
    const float* __restrict__ Wop, float* __restrict__ Wt, float* __restrict__ W1t,
    float* __restrict__ W3t, float* __restrict__ Wopt)
{
    int i = blockIdx.x * 256 + threadIdx.x;
    if (i < 62208) {
        int o = i / (48 * 27); int r = i % (48 * 27); int c = r / 27; int tap = r % 27;
        int og = o / 12, oi = o % 12;
        Wt[(((og * 27 + tap) * 48 + c) * 12) + oi] = W2[i];
    } else if (i < 62208 + 6912) {
        int j = i - 62208; int o = j / 144, c = j % 144;
        W1t[c * 48 + o] = W1[j];
    } else if (i < 62208 + 6912 + 2304) {
        int j = i - 62208 - 6912; int o = j / 48, c = j % 48;
        W3t[c * 48 + o] = W3[j];
    } else if (i < 62208 + 6912 + 2304 + 4608) {
        int j = i - 62208 - 6912 - 2304; int o = j / 96, q = j % 96;
        Wopt[q * 48 + o] = Wop[j];
    }
}

// ---------------- K1: upsample + concat + 1x1x1 conv (oh-split x4) ----------------
__global__ __launch_bounds__(128) void k_conv1(const float* __restrict__ x,
    const float* __restrict__ Hx, const float* __restrict__ W1t,
    const float* __restrict__ b1, float* __restrict__ h1)
{
    int t = blockIdx.x * 128 + threadIdx.x;   // grid.x = 216
    int oh = blockIdx.y * 12;                 // 0,12,24,36
    int b = t / P, p = t % P;
    int zi = p / 576, yi = (p / 24) % 24, xi_ = p % 24;
    float fpos; int z0, z1, y0, y1, x0, x1; float wz, wy, wx;
    fpos = (float)(zi * 11) / 23.0f; z0 = (int)floorf(fpos); wz = fpos - z0; z1 = min(z0 + 1, 11);
    fpos = (float)(yi * 11) / 23.0f; y0 = (int)floorf(fpos); wy = fpos - y0; y1 = min(y0 + 1, 11);
    fpos = (float)(xi_ * 11) / 23.0f; x0 = (int)floorf(fpos); wx = fpos - x0; x1 = min(x0 + 1, 11);
    int o000 = (z0*12+y0)*12+x0, o001 = (z0*12+y0)*12+x1;
    int o010 = (z0*12+y1)*12+x0, o011 = (z0*12+y1)*12+x1;
    int o100 = (z1*12+y0)*12+x0, o101 = (z1*12+y0)*12+x1;
    int o110 = (z1*12+y1)*12+x0, o111 = (z1*12+y1)*12+x1;
    float uz = 1.f - wz, uy = 1.f - wy, ux = 1.f - wx;
    float w000 = uz*uy*ux, w001 = uz*uy*wx, w010 = uz*wy*ux, w011 = uz*wy*wx;
    float w100 = wz*uy*ux, w101 = wz*uy*wx, w110 = wz*wy*ux, w111 = wz*wy*wx;

    float acc[12];
#pragma unroll
    for (int o = 0; o < 12; ++o) acc[o] = b1[oh + o];
    const float* xb = x + (size_t)b * 48 * 1728;
    for (int c0 = 0; c0 < 48; c0 += 4) {
        float a[4][8];
#pragma unroll
        for (int j = 0; j < 4; ++j) {
            const float* xc = xb + (c0 + j) * 1728;
            a[j][0] = xc[o000]; a[j][1] = xc[o001]; a[j][2] = xc[o010]; a[j][3] = xc[o011];
            a[j][4] = xc[o100]; a[j][5] = xc[o101]; a[j][6] = xc[o110]; a[j][7] = xc[o111];
        }
#pragma unroll
        for (int j = 0; j < 4; ++j) {
            float v = a[j][0]*w000 + a[j][1]*w001 + a[j][2]*w010 + a[j][3]*w011
                    + a[j][4]*w100 + a[j][5]*w101 + a[j][6]*w110 + a[j][7]*w111;
            const float* wr = W1t + (c0 + j) * 48 + oh;
#pragma unroll
            for (int o = 0; o < 12; ++o) acc[o] = fmaf(wr[o], v, acc[o]);
        }
    }
    const float* hb = Hx + (size_t)b * 96 * P + p;
    for (int c0 = 0; c0 < 96; c0 += 8) {
        float v[8];
#pragma unroll
        for (int j = 0; j < 8; ++j) v[j] = hb[(size_t)(c0 + j) * P];
#pragma unroll
        for (int j = 0; j < 8; ++j) {
            const float* wr = W1t + (48 + c0 + j) * 48 + oh;
#pragma unroll
            for (int o = 0; o < 12; ++o) acc[o] = fmaf(wr[o], v[j], acc[o]);
        }
    }
    float* out = h1 + (size_t)b * 48 * P + p;
#pragma unroll
    for (int o = 0; o < 12; ++o) out[(size_t)(oh+o) * P] = acc[o];
}

// ---------------- K2: fused 3x3x3 + 1x1x1 conv; [pos][ch] tile, b128 staging + taps ----------------
__global__ __launch_bounds__(512) void k_conv23(const float* __restrict__ h1,
    const float* __restrict__ Wt, const float* __restrict__ b2,
    const float* __restrict__ W3t, const float* __restrict__ b3,
    float* __restrict__ h3)
{
    __shared__ float tile[216 * 52];   // 43.9 KB, [pos][52-pad ch]; reused for exchange/h2t
    int blk = blockIdx.x;              // b*216 + tz*36 + ty*6 + tx
    int b = blk / 216; int r = blk % 216;
    int tz = r / 36, ty = (r / 6) % 6, tx = r % 6;
    int z0 = tz*4 - 1, y0 = ty*4 - 1, x0 = tx*4 - 1;
    // staging: thread = (q, c4); 4 coalesced loads + 1 ds_write_b128 (conflict-free)
    for (int i = threadIdx.x; i < 216 * 12; i += 512) {
        int q = i % 216; int c4 = (i / 216) * 4;
        int lz = q / 36, ly = (q / 6) % 6, lx = q % 6;
        int gz = z0 + lz, gy = y0 + ly, gx = x0 + lx;
        float4 v = {0.f, 0.f, 0.f, 0.f};
        if ((unsigned)gz < 24u && (unsigned)gy < 24u && (unsigned)gx < 24u) {
            size_t gp = (size_t)(gz*24 + gy)*24 + gx;
            const float* hp = h1 + ((size_t)(b*48 + c4)) * P + gp;
            v.x = hp[0];
            v.y = hp[P];
            v.z = hp[2*P];
            v.w = hp[3*P];
        }
        *(float4*)(&tile[q*52 + c4]) = v;
    }
    __syncthreads();
    int lp = threadIdx.x & 63;
    int w  = __builtin_amdgcn_readfirstlane((int)(threadIdx.x >> 6));  // 0..7 SGPR
    int og = w & 3, cc = w >> 2;
    int lz = lp >> 4, ly = (lp >> 2) & 3, lx = lp & 3;
    float acc[12];
#pragma unroll
    for (int i = 0; i < 12; ++i) acc[i] = cc ? 0.f : b2[og*12 + i];
#pragma unroll
    for (int dz = 0; dz < 3; ++dz)
#pragma unroll
    for (int dy = 0; dy < 3; ++dy)
#pragma unroll
    for (int dx = 0; dx < 3; ++dx) {
        int pos = (lz+dz)*36 + (ly+dy)*6 + (lx+dx);
        const float* tp = tile + pos*52 + cc*24;
        int tap = (dz*3 + dy)*3 + dx;
        const float* wt = Wt + (((size_t)og*27 + tap)*48 + cc*24)*12;  // uniform -> s_load
#pragma unroll
        for (int cq = 0; cq < 6; ++cq) {
            float4 v4 = *(const float4*)(tp + cq*4);     // ds_read_b128, bank-uniform
            const float* wq = wt + cq*48;
#pragma unroll
            for (int i = 0; i < 12; ++i) {
                acc[i] = fmaf(wq[i],      v4.x, acc[i]);
                acc[i] = fmaf(wq[12 + i], v4.y, acc[i]);
                acc[i] = fmaf(wq[24 + i], v4.z, acc[i]);
                acc[i] = fmaf(wq[36 + i], v4.w, acc[i]);
            }
        }
    }
    __syncthreads();                   // tile reads complete; reuse tile
    if (cc == 1) {
        float* ex = tile + og * 768;
#pragma unroll
        for (int i = 0; i < 12; ++i) ex[i*64 + lp] = acc[i];  // stride-64: conflict-free
    }
    __syncthreads();
    if (cc == 0) {
        const float* ex = tile + og * 768;
        float* ht = tile + 3072;       // h2 tile [48][64]
#pragma unroll
        for (int i = 0; i < 12; ++i)
            ht[(og*12 + i)*64 + lp] = acc[i] + ex[i*64 + lp];
    }
    __syncthreads();
    // ---- conv3 (1x1x1, 48->48) in-block: wave w handles 6 output channels ----
    const float* ht = tile + 3072;
    int oc0 = w * 6;
    float acc3[6];
#pragma unroll
    for (int j = 0; j < 6; ++j) acc3[j] = b3[oc0 + j];        // uniform -> s_load
    for (int c = 0; c < 48; ++c) {
        float v = ht[c*64 + lp];                              // coalesced, conflict-free
        const float* wr = W3t + c*48 + oc0;                   // uniform -> s_load
#pragma unroll
        for (int j = 0; j < 6; ++j) acc3[j] = fmaf(wr[j], v, acc3[j]);
    }
    int gz = tz*4 + lz, gy = ty*4 + ly, gx = tx*4 + lx;
    size_t pp = (size_t)(gz*24 + gy)*24 + gx;
#pragma unroll
    for (int j = 0; j < 6; ++j)
        h3[((size_t)(b*48) + oc0 + j) * P + pp] = acc3[j];
}

// ---------------- K4: fused instance-norm stats + normalize + SELU (1024 thr) ----------------
__global__ __launch_bounds__(1024) void k_instnorm(float* __restrict__ h3)
{
    int bc = blockIdx.x;   // 0..95
    float4* src = (float4*)(h3 + (size_t)bc * P);   // 3456 float4
    float s = 0.f, s2 = 0.f;
    for (int i = threadIdx.x; i < 3456; i += 1024) {
        float4 v = src[i];
        s  += v.x + v.y + v.z + v.w;
        s2 += v.x*v.x + v.y*v.y + v.z*v.z + v.w*v.w;
    }
    __shared__ float rs[16], rs2[16], mv[2];
    for (int off = 32; off; off >>= 1) { s += __shfl_down(s, off); s2 += __shfl_down(s2, off); }
    int wid = threadIdx.x >> 6;
    if ((threadIdx.x & 63) == 0) { rs[wid] = s; rs2[wid] = s2; }
    __syncthreads();
    if (threadIdx.x == 0) {
        s = 0.f; s2 = 0.f;
#pragma unroll
        for (int k = 0; k < 16; ++k) { s += rs[k]; s2 += rs2[k]; }
        float m = s / (float)P;
        float var = s2 / (float)P - m * m;
        mv[0] = m; mv[1] = rsqrtf(var + 1e-5f);
    }
    __syncthreads();
    float m = mv[0], istd = mv[1];
    const float kS = 1.0507009873554805f, kA = 1.6732632423543772f;
    for (int i = threadIdx.x; i < 3456; i += 1024) {
        float4 v = src[i];
        float a0 = (v.x - m) * istd, a1 = (v.y - m) * istd;
        float a2 = (v.z - m) * istd, a3 = (v.w - m) * istd;
        v.x = a0 > 0.f ? kS * a0 : kS * kA * expm1f(a0);
        v.y = a1 > 0.f ? kS * a1 : kS * kA * expm1f(a1);
        v.z = a2 > 0.f ? kS * a2 : kS * kA * expm1f(a2);
        v.w = a3 > 0.f ? kS * a3 : kS * kA * expm1f(a3);
        src[i] = v;
    }
}

// ---------------- K6: in_proj via scalar-loaded activations (l-tile 24) ----------------
__global__ __launch_bounds__(192) void k_inproj(const float* __restrict__ Lx,
    const float* __restrict__ Wip, float* __restrict__ xi, float* __restrict__ z)
{
    int b = blockIdx.x / 576; int l0 = (blockIdx.x % 576) * 24;
    int e = threadIdx.x;   // 0..191
    float w[48];
#pragma unroll
    for (int c = 0; c < 48; ++c) w[c] = Wip[e*48 + c];
    float acc[24];
#pragma unroll
    for (int ll = 0; ll < 24; ++ll) acc[ll] = 0.f;
    const float* ub = Lx + (size_t)b * 48 * P + l0;   // wave-uniform
#pragma unroll 2
    for (int c = 0; c < 48; ++c) {
        const float* ur = ub + (size_t)c * P;          // uniform -> s_load
#pragma unroll
        for (int ll = 0; ll < 24; ++ll) acc[ll] = fmaf(w[c], ur[ll], acc[ll]);
    }
    float* dst = (e < 96) ? (xi + ((size_t)b * L + l0) * 96 + e)
                          : (z  + ((size_t)b * L + l0) * 96 + (e - 96));
#pragma unroll
    for (int ll = 0; ll < 24; ++ll) dst[(size_t)ll * 96] = acc[ll];
}

// ---------------- K7+K8 fused: conv1d+silu -> x_proj -> dt_proj+softplus (TL=32) ----------------
__global__ __launch_bounds__(256) void k_fxproj(const float* __restrict__ xi,
    const float* __restrict__ cw, const float* __restrict__ cb,
    const float* __restrict__ Wxp, const float* __restrict__ Wdt,
    const float* __restrict__ bdt, float* __restrict__ xs,
    float* __restrict__ delta, float* __restrict__ Bm, float* __restrict__ Cm)
{
    __shared__ float xs_t[TL][100];   // 12.8 KB, stride-100 pad
    __shared__ float wx_t[35][100];   // 14 KB
    __shared__ float wd_t[96][4];     // Wdt rows + bias packed
    __shared__ float dt_t[TL][4];
    int blk = blockIdx.x;             // 864 = NB * 432
    int b = blk / 432; int l0 = (blk % 432) * TL;
    int tid = threadIdx.x;

    for (int i = tid; i < 35 * 96; i += 256) wx_t[i / 96][i % 96] = Wxp[i];
    for (int i = tid; i < 96 * 3; i += 256) wd_t[i / 3][i % 3] = Wdt[i];
    for (int i = tid; i < 96; i += 256) wd_t[i][3] = bdt[i];

    int row = tid >> 3;               // 0..31
    int q8  = tid & 7;
    int d0  = q8 * 12;                // 12 d per thread
    int l = l0 + row;
    size_t t_glob = (size_t)b * L + l;
    const float* xib = xi + (size_t)b * L * 96;
    float* xsg = xs + t_glob * 96 + d0;
    int ls0 = l - 3;
    // ---- Phase B: conv1d + silu (3 float4 groups per thread) ----
#pragma unroll
    for (int jq = 0; jq < 3; ++jq) {
        int d = d0 + jq * 4;
        float4 t0 = *(const float4*)(cw + 4 * (d + 0));
        float4 t1 = *(const float4*)(cw + 4 * (d + 1));
        float4 t2 = *(const float4*)(cw + 4 * (d + 2));
        float4 t3 = *(const float4*)(cw + 4 * (d + 3));
        float4 acc = *(const float4*)(cb + d);
        float4 q0 = {0.f,0.f,0.f,0.f}, q1 = q0, q2 = q0;
        if (ls0 + 0 >= 0) q0 = *(const float4*)(xib + (size_t)(ls0 + 0) * 96 + d);
        if (ls0 + 1 >= 0) q1 = *(const float4*)(xib + (size_t)(ls0 + 1) * 96 + d);
        if (ls0 + 2 >= 0) q2 = *(const float4*)(xib + (size_t)(ls0 + 2) * 96 + d);
        float4 q3 = *(const float4*)(xib + (size_t)(ls0 + 3) * 96 + d);
        acc.x += t0.x*q0.x + t0.y*q1.x + t0.z*q2.x + t0.w*q3.x;
        acc.y += t1.x*q0.y + t1.y*q1.y + t1.z*q2.y + t1.w*q3.y;
        acc.z += t2.x*q0.z + t2.y*q1.z + t2.z*q2.z + t2.w*q3.z;
        acc.w += t3.x*q0.w + t3.y*q1.w + t3.z*q2.w + t3.w*q3.w;
        acc.x = siluf(acc.x); acc.y = siluf(acc.y);
        acc.z = siluf(acc.z); acc.w = siluf(acc.w);
        *(float4*)(&xs_t[row][d0 + jq * 4]) = acc;
        *(float4*)(xsg + jq * 4) = acc;
    }
    __syncthreads();

    // ---- Phase C: x_proj; thread (row, q8) computes e = q8 + 8k, k<5 ----
    float acc5[5];
#pragma unroll
    for (int k = 0; k < 5; ++k) acc5[k] = 0.f;
    const float* xrow = &xs_t[row][0];
#pragma unroll 4
    for (int j = 0; j < 24; ++j) {
        float4 xv = *(const float4*)(xrow + 4 * j);
#pragma unroll
        for (int k = 0; k < 5; ++k) {
            int e = q8 + 8 * k;
            if (e < 35) {
                float4 wv = *(const float4*)(&wx_t[e][4 * j]);
                acc5[k] = fmaf(wv.x, xv.x, fmaf(wv.y, xv.y,
                          fmaf(wv.z, xv.z, fmaf(wv.w, xv.w, acc5[k]))));
            }
        }
    }
#pragma unroll
    for (int k = 0; k < 5; ++k) {
        int e = q8 + 8 * k;
        if (e < 35) {
            if (e < 3)       dt_t[row][e] = acc5[k];
            else if (e < 19) Bm[t_glob * 16 + (e - 3)]  = acc5[k];
            else             Cm[t_glob * 16 + (e - 19)] = acc5[k];
        }
    }
    __syncthreads();

    // ---- Phase D: delta = softplus(Wdt . dt + bias), 12 d per thread ----
    float dt0 = dt_t[row][0], dt1 = dt_t[row][1], dt2 = dt_t[row][2];
    float* dl = delta + t_glob * 96 + d0;
#pragma unroll
    for (int jq = 0; jq < 3; ++jq) {
        float4 o;
        {
            float4 wv = *(const float4*)(&wd_t[d0 + jq*4 + 0][0]);
            o.x = softplusf(fmaf(wv.x, dt0, fmaf(wv.y, dt1, fmaf(wv.z, dt2, wv.w))));
        }
        {
            float4 wv = *(const float4*)(&wd_t[d0 + jq*4 + 1][0]);
            o.y = softplusf(fmaf(wv.x, dt0, fmaf(wv.y, dt1, fmaf(wv.z, dt2, wv.w))));
        }
        {
            float4 wv = *(const float4*)(&wd_t[d0 + jq*4 + 2][0]);
            o.z = softplusf(fmaf(wv.x, dt0, fmaf(wv.y, dt1, fmaf(wv.z, dt2, wv.w))));
        }
        {
            float4 wv = *(const float4*)(&wd_t[d0 + jq*4 + 3][0]);
            o.w = softplusf(fmaf(wv.x, dt0, fmaf(wv.y, dt1, fmaf(wv.z, dt2, wv.w))));
        }
        *(float4*)(dl + jq * 4) = o;
    }
}

// ---------------- K9: scan phase 1 — software-pipelined (CHUNK=32) ----------------
__global__ __launch_bounds__(256) void k_scan1(const float* __restrict__ delta,
    const float* __restrict__ xs, const float* __restrict__ Bm,
    const float* __restrict__ Alog, float* __restrict__ Aprod, float* __restrict__ hend)
{
    int wid = (blockIdx.x * 256 + threadIdx.x) >> 6;
    int lane = threadIdx.x & 63;
    int dg = wid % 24; int ch = (wid / 24) % NCK; int b = wid / (24 * NCK);
    int dl = lane >> 4, n = lane & 15;
    int d = dg * 4 + dl;
    float A = -__expf(Alog[d*16 + n]);
    float h = 0.f, ap = 1.f;
    int t0 = ch * CHUNK;
    const float* dp = delta + ((size_t)b * L + t0) * 96 + d;
    const float* xp = xs    + ((size_t)b * L + t0) * 96 + d;
    const float* bp = Bm    + ((size_t)b * L + t0) * 16 + n;

    float dA0, dA1, dA2, dA3, xA0, xA1, xA2, xA3, bA0, bA1, bA2, bA3;
    float dB0, dB1, dB2, dB3, xB0, xB1, xB2, xB3, bB0, bB1, bB2, bB3;
#define LD1(s, T) do { \
    d##s##0 = dp[(size_t)(T)*96];     x##s##0 = xp[(size_t)(T)*96];     b##s##0 = bp[(size_t)(T)*16]; \
    d##s##1 = dp[(size_t)((T)+1)*96]; x##s##1 = xp[(size_t)((T)+1)*96]; b##s##1 = bp[(size_t)((T)+1)*16]; \
    d##s##2 = dp[(size_t)((T)+2)*96]; x##s##2 = xp[(size_t)((T)+2)*96]; b##s##2 = bp[(size_t)((T)+2)*16]; \
    d##s##3 = dp[(size_t)((T)+3)*96]; x##s##3 = xp[(size_t)((T)+3)*96]; b##s##3 = bp[(size_t)((T)+3)*16]; \
  } while (0)
#define CMP1(s) do { \
    float e0 = __expf(d##s##0 * A); float e1 = __expf(d##s##1 * A); \
    float e2 = __expf(d##s##2 * A); float e3 = __expf(d##s##3 * A); \
    h = fmaf(e0, h, d##s##0 * x##s##0 * b##s##0); \
    h = fmaf(e1, h, d##s##1 * x##s##1 * b##s##1); \
    h = fmaf(e2, h, d##s##2 * x##s##2 * b##s##2); \
    h = fmaf(e3, h, d##s##3 * x##s##3 * b##s##3); \
    ap *= e0 * e1 * e2 * e3; \
  } while (0)

    LD1(A, 0);
#pragma unroll 1
    for (int t = 0; t < CHUNK; t += 8) {
        LD1(B, t + 4);
        CMP1(A);
        if (t + 8 < CHUNK) LD1(A, t + 8);
        CMP1(B);
    }
#undef LD1
#undef CMP1
    size_t idx = (((size_t)b * NCK + ch) * 96 + d) * 16 + n;
    Aprod[idx] = ap;
    hend[idx]  = h;
}

// ---------------- K10: scan phase 2 (NCK=432; hin may alias Aprod — writes trail reads) ----------------
__global__ __launch_bounds__(256) void k_scan2(const float* Aprod,
    const float* __restrict__ hend, float* hin)
{
    int t = blockIdx.x * 256 + threadIdx.x;   // NB*1536 exact
    int b = t / 1536; int dn = t % 1536;
    const float* ap = Aprod + (size_t)b * NCK * 1536 + dn;
    const float* he = hend  + (size_t)b * NCK * 1536 + dn;
    float* hi       = hin   + (size_t)b * NCK * 1536 + dn;
    float carry = 0.f;
    float aA0, aA1, aA2, aA3, hA0, hA1, hA2, hA3;
    float aB0, aB1, aB2, aB3, hB0, hB1, hB2, hB3;
#define LD2(s, J) do { \
    a##s##0 = ap[(size_t)(J)*1536];     h##s##0 = he[(size_t)(J)*1536]; \
    a##s##1 = ap[(size_t)((J)+1)*1536]; h##s##1 = he[(size_t)((J)+1)*1536]; \
    a##s##2 = ap[(size_t)((J)+2)*1536]; h##s##2 = he[(size_t)((J)+2)*1536]; \
    a##s##3 = ap[(size_t)((J)+3)*1536]; h##s##3 = he[(size_t)((J)+3)*1536]; \
  } while (0)
#define CMP2(s, J) do { \
    hi[(size_t)(J)*1536]     = carry; carry = fmaf(a##s##0, carry, h##s##0); \
    hi[(size_t)((J)+1)*1536] = carry; carry = fmaf(a##s##1, carry, h##s##1); \
    hi[(size_t)((J)+2)*1536] = carry; carry = fmaf(a##s##2, carry, h##s##2); \
    hi[(size_t)((J)+3)*1536] = carry; carry = fmaf(a##s##3, carry, h##s##3); \
  } while (0)
    LD2(A, 0);
#pragma unroll 1
    for (int j = 0; j < NCK; j += 8) {
        LD2(B, j + 4);
        CMP2(A, j);
        if (j + 8 < NCK) LD2(A, j + 8);
        CMP2(B, j + 4);
    }
#undef LD2
#undef CMP2
}

// ---------------- K11: scan phase 3 — software-pipelined replay + y (CHUNK=32) ----------------
__global__ __launch_bounds__(256) void k_scan3(const float* __restrict__ delta,
    float* __restrict__ xs, const float* __restrict__ Bm, const float* __restrict__ Cm,
    const float* __restrict__ z, const float* __restrict__ Alog,
    const float* __restrict__ Dp, const float* __restrict__ hin)
{
    int wid = (blockIdx.x * 256 + threadIdx.x) >> 6;
    int lane = threadIdx.x & 63;
    int dg = wid % 24; int ch = (wid / 24) % NCK; int b = wid / (24 * NCK);
    int dl = lane >> 4, n = lane & 15;
    int d = dg * 4 + dl;
    float A = -__expf(Alog[d*16 + n]);
    float Dv = Dp[d];
    size_t cidx = (((size_t)b * NCK + ch) * 96 + d) * 16 + n;
    float h = hin[cidx];
    int t0 = ch * CHUNK;
    const float* dp = delta + ((size_t)b * L + t0) * 96 + d;
    float* xp       = xs    + ((size_t)b * L + t0) * 96 + d;
    const float* bp = Bm    + ((size_t)b * L + t0) * 16 + n;
    const float* cp = Cm    + ((size_t)b * L + t0) * 16 + n;
    const float* zp = z     + ((size_t)b * L + t0) * 96 + d;

    float dA0, dA1, dA2, dA3, xA0, xA1, xA2, xA3, bA0, bA1, bA2, bA3, cA0, cA1, cA2, cA3, zA0, zA1, zA2, zA3;
    float dB0, dB1, dB2, dB3, xB0, xB1, xB2, xB3, bB0, bB1, bB2, bB3, cB0, cB1, cB2, cB3, zB0, zB1, zB2, zB3;
#define LD3(s, T) do { \
    d##s##0 = dp[(size_t)(T)*96];     x##s##0 = xp[(size_t)(T)*96];     b##s##0 = bp[(size_t)(T)*16]; \
    c##s##0 = cp[(size_t)(T)*16];     z##s##0 = zp[(size_t)(T)*96]; \
    d##s##1 = dp[(size_t)((T)+1)*96]; x##s##1 = xp[(size_t)((T)+1)*96]; b##s##1 = bp[(size_t)((T)+1)*16]; \
    c##s##1 = cp[(size_t)((T)+1)*16]; z##s##1 = zp[(size_t)((T)+1)*96]; \
    d##s##2 = dp[(size_t)((T)+2)*96]; x##s##2 = xp[(size_t)((T)+2)*96]; b##s##2 = bp[(size_t)((T)+2)*16]; \
    c##s##2 = cp[(size_t)((T)+2)*16]; z##s##2 = zp[(size_t)((T)+2)*96]; \
    d##s##3 = dp[(size_t)((T)+3)*96]; x##s##3 = xp[(size_t)((T)+3)*96]; b##s##3 = bp[(size_t)((T)+3)*16]; \
    c##s##3 = cp[(size_t)((T)+3)*16]; z##s##3 = zp[(size_t)((T)+3)*96]; \
  } while (0)
#define STEP3(DEL, XV, BV, CV, ZV, T) do { \
    float dAv = __expf((DEL) * A); \
    h = fmaf(dAv, h, (DEL) * (XV) * (BV)); \
    float yc = h * (CV); \
    yc += __shfl_xor(yc, 8); \
    yc += __shfl_xor(yc, 4); \
    yc += __shfl_xor(yc, 2); \
    yc += __shfl_xor(yc, 1); \
    if (n == 0) xp[(size_t)(T)*96] = fmaf(Dv, (XV), yc) * siluf(ZV); \
  } while (0)
#define CMP3(s, T) do { \
    STEP3(d##s##0, x##s##0, b##s##0, c##s##0, z##s##0, (T)); \
    STEP3(d##s##1, x##s##1, b##s##1, c##s##1, z##s##1, (T)+1); \
    STEP3(d##s##2, x##s##2, b##s##2, c##s##2, z##s##2, (T)+2); \
    STEP3(d##s##3, x##s##3, b##s##3, c##s##3, z##s##3, (T)+3); \
  } while (0)

    LD3(A, 0);
#pragma unroll 1
    for (int t = 0; t < CHUNK; t += 8) {
        LD3(B, t + 4);
        CMP3(A, t);
        if (t + 8 < CHUNK) LD3(A, t + 8);
        CMP3(B, t + 4);
    }
#undef LD3
#undef STEP3
#undef CMP3
}

// ---------------- K12: out_proj + residual (oh-split x4) ----------------
__global__ __launch_bounds__(128) void k_outproj(const float* __restrict__ y,
    const float* __restrict__ Wopt, const float* __restrict__ Lx, float* __restrict__ out)
{
    int t = blockIdx.x * 128 + threadIdx.x;  // grid.x = 216
    int oh = blockIdx.y * 12;                // 0,12,24,36
    int b = t / P, p = t % P;
    const float* yr = y + (size_t)t * 96;
    float acc[12];
#pragma unroll
    for (int o = 0; o < 12; ++o) acc[o] = 0.f;
#pragma unroll
    for (int i = 0; i < 24; ++i) {
        float4 v4 = ((const float4*)yr)[i];
        const float* w0 = Wopt + (i*4) * 48 + oh;
        const float* w1 = Wopt + (i*4 + 1) * 48 + oh;
        const float* w2 = Wopt + (i*4 + 2) * 48 + oh;
        const float* w3 = Wopt + (i*4 + 3) * 48 + oh;
#pragma unroll
        for (int o = 0; o < 12; ++o) {
            acc[o] = fmaf(w0[o], v4.x, acc[o]);
            acc[o] = fmaf(w1[o], v4.y, acc[o]);
            acc[o] = fmaf(w2[o], v4.z, acc[o]);
            acc[o] = fmaf(w3[o], v4.w, acc[o]);
        }
    }
    const float* lx = Lx + (size_t)b * 48 * P + p;
    float* op = out + (size_t)b * 48 * P + p;
#pragma unroll
    for (int o = 0; o < 12; ++o) op[(size_t)(oh+o) * P] = acc[o] + lx[(size_t)(oh+o) * P];
}

extern "C" void kernel_launch(void* const* d_in, const int* in_sizes, int n_in,
                              void* d_out, int out_size, void* d_ws, size_t ws_size,
                              hipStream_t stream) {
    const float* x        = (const float*)d_in[0];
    const float* Hx       = (const float*)d_in[1];
    const float* W1       = (const float*)d_in[2];
    const float* b1       = (const float*)d_in[3];
    const float* W2       = (const float*)d_in[4];
    const float* b2       = (const float*)d_in[5];
    const float* W3       = (const float*)d_in[6];
    const float* b3       = (const float*)d_in[7];
    const float* in_proj  = (const float*)d_in[8];
    const float* conv1d_w = (const float*)d_in[9];
    const float* conv1d_b = (const float*)d_in[10];
    const float* x_proj   = (const float*)d_in[11];
    const float* dt_proj  = (const float*)d_in[12];
    const float* dt_bias  = (const float*)d_in[13];
    const float* A_log    = (const float*)d_in[14];
    const float* D_param  = (const float*)d_in[15];
    const float* out_proj = (const float*)d_in[16];
    float* out = (float*)d_out;

    float* ws = (float*)d_ws;
    const size_t SZ_BCP = (size_t)NB * 48 * P;      // 1,327,104
    const size_t SZ_BLD = (size_t)NB * L * 96;      // 2,654,208
    const size_t SZ_BLN = (size_t)NB * L * 16;      //   442,368
    const size_t SZ_CK  = (size_t)NB * NCK * 1536;  // 1,327,104 (CHUNK=32)
    float* bufA  = ws;                    // h1; later delta (spans bufA+bufB)
    float* bufB  = bufA + SZ_BCP;         // (free; part of delta)
    float* bufC  = bufB + SZ_BCP;         // h3 -> Lx (in place)
    float* xib   = bufC + SZ_BCP;         // xi; scan bufs overlay after fxproj
    float* zb    = xib  + SZ_BLD;         // z
    float* xsb   = zb   + SZ_BLD;         // xs, then y (in place)
    float* Bmb   = xsb  + SZ_BLD;
    float* Cmb   = Bmb  + SZ_BLN;
    float* stats = Cmb  + SZ_BLN;         // (unused; layout keep)
    float* Wtb   = stats + 192;           // 62,208 (W2 reshaped)
    float* W1tb  = Wtb + 62208;           // 6,912
    float* W3tb  = W1tb + 6912;           // 2,304
    float* Woptb = W3tb + 2304;           // 4,608
    float* deltab = bufA;                 // reuses h1 region (free after k_conv23)
    // scan intermediates overlay xi (dead after k_fxproj): Apr+hend = 2*SZ_CK = SZ_BLD;
    // hin ALIASES Apr (scan2 writes trail its reads by >=4 elements)
    float* Apr   = xib;
    float* hendb = xib + SZ_CK;
    float* hinb  = Apr;

    k_wtrans<<<297, 256, 0, stream>>>(W2, W1, W3, out_proj, Wtb, W1tb, W3tb, Woptb);
    k_conv1<<<dim3(216, 4), 128, 0, stream>>>(x, Hx, W1tb, b1, bufA);
    k_conv23<<<NB * 216, 512, 0, stream>>>(bufA, Wtb, b2, W3tb, b3, bufC);
    k_instnorm<<<NB * 48, 1024, 0, stream>>>(bufC);
    k_inproj<<<NB * 576, 192, 0, stream>>>(bufC, in_proj, xib, zb);
    k_fxproj<<<NB * 432, 256, 0, stream>>>(xib, conv1d_w, conv1d_b, x_proj, dt_proj,
                                           dt_bias, xsb, deltab, Bmb, Cmb);
    k_scan1<<<(NB * NCK * 24) / 4, 256, 0, stream>>>(deltab, xsb, Bmb, A_log, Apr, hendb);
    k_scan2<<<12, 256, 0, stream>>>(Apr, hendb, hinb);
    k_scan3<<<(NB * NCK * 24) / 4, 256, 0, stream>>>(deltab, xsb, Bmb, Cmb, zb, A_log,
                                                     D_param, hinb);
    k_outproj<<<dim3(216, 4), 128, 0, stream>>>(xsb, Woptb, bufC, out);
}

// Round 18
// 262.144 us; speedup vs baseline: 1.0523x; 1.0523x over previous
//
#include <hip/hip_runtime.h>
#include <math.h>

#define NB 2
#define NCH 48
#define P 13824        // 24^3
#define DI 96
#define NSTATE 16
#define L 13824
#define CHUNK 64
#define NCK 216        // L / CHUNK
#define TL 32          // rows per fused-xproj block

__device__ __forceinline__ float siluf(float x) { return x / (1.f + __expf(-x)); }
__device__ __forceinline__ float softplusf(float x) {
    return x > 0.f ? x + log1pf(expf(-x)) : log1pf(expf(x));
}

// ---------------- K0: weight reshuffles ----------------
// W2 [48o][48c][27t] -> Wt [4og][27t][48c][12oi]
__global__ __launch_bounds__(256) void k_wtrans(const float* __restrict__ W2,
    const float* __restrict__ W1, const float* __restrict__ W3,
    const float* __restrict__ Wop, float* __restrict__ Wt, float* __restrict__ W1t,
    float* __restrict__ W3t, float* __restrict__ Wopt)
{
    int i = blockIdx.x * 256 + threadIdx.x;
    if (i < 62208) {
        int o = i / (48 * 27); int r = i % (48 * 27); int c = r / 27; int tap = r % 27;
        int og = o / 12, oi = o % 12;
        Wt[(((og * 27 + tap) * 48 + c) * 12) + oi] = W2[i];
    } else if (i < 62208 + 6912) {
        int j = i - 62208; int o = j / 144, c = j % 144;
        W1t[c * 48 + o] = W1[j];
    } else if (i < 62208 + 6912 + 2304) {
        int j = i - 62208 - 6912; int o = j / 48, c = j % 48;
        W3t[c * 48 + o] = W3[j];
    } else if (i < 62208 + 6912 + 2304 + 4608) {
        int j = i - 62208 - 6912 - 2304; int o = j / 96, q = j % 96;
        Wopt[q * 48 + o] = Wop[j];
    }
}

// ---------------- K1: upsample + concat + 1x1x1 conv (oh-split x4) ----------------
__global__ __launch_bounds__(128) void k_conv1(const float* __restrict__ x,
    const float* __restrict__ Hx, const float* __restrict__ W1t,
    const float* __restrict__ b1, float* __restrict__ h1)
{
    int t = blockIdx.x * 128 + threadIdx.x;   // grid.x = 216
    int oh = blockIdx.y * 12;                 // 0,12,24,36
    int b = t / P, p = t % P;
    int zi = p / 576, yi = (p / 24) % 24, xi_ = p % 24;
    float fpos; int z0, z1, y0, y1, x0, x1; float wz, wy, wx;
    fpos = (float)(zi * 11) / 23.0f; z0 = (int)floorf(fpos); wz = fpos - z0; z1 = min(z0 + 1, 11);
    fpos = (float)(yi * 11) / 23.0f; y0 = (int)floorf(fpos); wy = fpos - y0; y1 = min(y0 + 1, 11);
    fpos = (float)(xi_ * 11) / 23.0f; x0 = (int)floorf(fpos); wx = fpos - x0; x1 = min(x0 + 1, 11);
    int o000 = (z0*12+y0)*12+x0, o001 = (z0*12+y0)*12+x1;
    int o010 = (z0*12+y1)*12+x0, o011 = (z0*12+y1)*12+x1;
    int o100 = (z1*12+y0)*12+x0, o101 = (z1*12+y0)*12+x1;
    int o110 = (z1*12+y1)*12+x0, o111 = (z1*12+y1)*12+x1;
    float uz = 1.f - wz, uy = 1.f - wy, ux = 1.f - wx;
    float w000 = uz*uy*ux, w001 = uz*uy*wx, w010 = uz*wy*ux, w011 = uz*wy*wx;
    float w100 = wz*uy*ux, w101 = wz*uy*wx, w110 = wz*wy*ux, w111 = wz*wy*wx;

    float acc[12];
#pragma unroll
    for (int o = 0; o < 12; ++o) acc[o] = b1[oh + o];
    const float* xb = x + (size_t)b * 48 * 1728;
    for (int c0 = 0; c0 < 48; c0 += 4) {
        float a[4][8];
#pragma unroll
        for (int j = 0; j < 4; ++j) {
            const float* xc = xb + (c0 + j) * 1728;
            a[j][0] = xc[o000]; a[j][1] = xc[o001]; a[j][2] = xc[o010]; a[j][3] = xc[o011];
            a[j][4] = xc[o100]; a[j][5] = xc[o101]; a[j][6] = xc[o110]; a[j][7] = xc[o111];
        }
#pragma unroll
        for (int j = 0; j < 4; ++j) {
            float v = a[j][0]*w000 + a[j][1]*w001 + a[j][2]*w010 + a[j][3]*w011
                    + a[j][4]*w100 + a[j][5]*w101 + a[j][6]*w110 + a[j][7]*w111;
            const float* wr = W1t + (c0 + j) * 48 + oh;
#pragma unroll
            for (int o = 0; o < 12; ++o) acc[o] = fmaf(wr[o], v, acc[o]);
        }
    }
    const float* hb = Hx + (size_t)b * 96 * P + p;
    for (int c0 = 0; c0 < 96; c0 += 8) {
        float v[8];
#pragma unroll
        for (int j = 0; j < 8; ++j) v[j] = hb[(size_t)(c0 + j) * P];
#pragma unroll
        for (int j = 0; j < 8; ++j) {
            const float* wr = W1t + (48 + c0 + j) * 48 + oh;
#pragma unroll
            for (int o = 0; o < 12; ++o) acc[o] = fmaf(wr[o], v[j], acc[o]);
        }
    }
    float* out = h1 + (size_t)b * 48 * P + p;
#pragma unroll
    for (int o = 0; o < 12; ++o) out[(size_t)(oh+o) * P] = acc[o];
}

// ---------------- K2: fused 3x3x3 + 1x1x1 conv; [pos][ch] tile, b128 staging + taps ----------------
__global__ __launch_bounds__(512) void k_conv23(const float* __restrict__ h1,
    const float* __restrict__ Wt, const float* __restrict__ b2,
    const float* __restrict__ W3t, const float* __restrict__ b3,
    float* __restrict__ h3)
{
    __shared__ float tile[216 * 52];   // 43.9 KB, [pos][52-pad ch]; reused for exchange/h2t
    int blk = blockIdx.x;              // b*216 + tz*36 + ty*6 + tx
    int b = blk / 216; int r = blk % 216;
    int tz = r / 36, ty = (r / 6) % 6, tx = r % 6;
    int z0 = tz*4 - 1, y0 = ty*4 - 1, x0 = tx*4 - 1;
    // staging: thread = (q, c4); 4 coalesced loads + 1 ds_write_b128 (conflict-free)
    for (int i = threadIdx.x; i < 216 * 12; i += 512) {
        int q = i % 216; int c4 = (i / 216) * 4;
        int lz = q / 36, ly = (q / 6) % 6, lx = q % 6;
        int gz = z0 + lz, gy = y0 + ly, gx = x0 + lx;
        float4 v = {0.f, 0.f, 0.f, 0.f};
        if ((unsigned)gz < 24u && (unsigned)gy < 24u && (unsigned)gx < 24u) {
            size_t gp = (size_t)(gz*24 + gy)*24 + gx;
            const float* hp = h1 + ((size_t)(b*48 + c4)) * P + gp;
            v.x = hp[0];
            v.y = hp[P];
            v.z = hp[2*P];
            v.w = hp[3*P];
        }
        *(float4*)(&tile[q*52 + c4]) = v;
    }
    __syncthreads();
    int lp = threadIdx.x & 63;
    int w  = __builtin_amdgcn_readfirstlane((int)(threadIdx.x >> 6));  // 0..7 SGPR
    int og = w & 3, cc = w >> 2;
    int lz = lp >> 4, ly = (lp >> 2) & 3, lx = lp & 3;
    float acc[12];
#pragma unroll
    for (int i = 0; i < 12; ++i) acc[i] = cc ? 0.f : b2[og*12 + i];
#pragma unroll
    for (int dz = 0; dz < 3; ++dz)
#pragma unroll
    for (int dy = 0; dy < 3; ++dy)
#pragma unroll
    for (int dx = 0; dx < 3; ++dx) {
        int pos = (lz+dz)*36 + (ly+dy)*6 + (lx+dx);
        const float* tp = tile + pos*52 + cc*24;
        int tap = (dz*3 + dy)*3 + dx;
        const float* wt = Wt + (((size_t)og*27 + tap)*48 + cc*24)*12;  // uniform -> s_load
#pragma unroll
        for (int cq = 0; cq < 6; ++cq) {
            float4 v4 = *(const float4*)(tp + cq*4);     // ds_read_b128, bank-uniform
            const float* wq = wt + cq*48;
#pragma unroll
            for (int i = 0; i < 12; ++i) {
                acc[i] = fmaf(wq[i],      v4.x, acc[i]);
                acc[i] = fmaf(wq[12 + i], v4.y, acc[i]);
                acc[i] = fmaf(wq[24 + i], v4.z, acc[i]);
                acc[i] = fmaf(wq[36 + i], v4.w, acc[i]);
            }
        }
    }
    __syncthreads();                   // tile reads complete; reuse tile
    if (cc == 1) {
        float* ex = tile + og * 768;
#pragma unroll
        for (int i = 0; i < 12; ++i) ex[i*64 + lp] = acc[i];  // stride-64: conflict-free
    }
    __syncthreads();
    if (cc == 0) {
        const float* ex = tile + og * 768;
        float* ht = tile + 3072;       // h2 tile [48][64]
#pragma unroll
        for (int i = 0; i < 12; ++i)
            ht[(og*12 + i)*64 + lp] = acc[i] + ex[i*64 + lp];
    }
    __syncthreads();
    // ---- conv3 (1x1x1, 48->48) in-block: wave w handles 6 output channels ----
    const float* ht = tile + 3072;
    int oc0 = w * 6;
    float acc3[6];
#pragma unroll
    for (int j = 0; j < 6; ++j) acc3[j] = b3[oc0 + j];        // uniform -> s_load
    for (int c = 0; c < 48; ++c) {
        float v = ht[c*64 + lp];                              // coalesced, conflict-free
        const float* wr = W3t + c*48 + oc0;                   // uniform -> s_load
#pragma unroll
        for (int j = 0; j < 6; ++j) acc3[j] = fmaf(wr[j], v, acc3[j]);
    }
    int gz = tz*4 + lz, gy = ty*4 + ly, gx = tx*4 + lx;
    size_t pp = (size_t)(gz*24 + gy)*24 + gx;
#pragma unroll
    for (int j = 0; j < 6; ++j)
        h3[((size_t)(b*48) + oc0 + j) * P + pp] = acc3[j];
}

// ---------------- K4: fused instance-norm stats + normalize + SELU (1024 thr) ----------------
__global__ __launch_bounds__(1024) void k_instnorm(float* __restrict__ h3)
{
    int bc = blockIdx.x;   // 0..95
    float4* src = (float4*)(h3 + (size_t)bc * P);   // 3456 float4
    float s = 0.f, s2 = 0.f;
    for (int i = threadIdx.x; i < 3456; i += 1024) {
        float4 v = src[i];
        s  += v.x + v.y + v.z + v.w;
        s2 += v.x*v.x + v.y*v.y + v.z*v.z + v.w*v.w;
    }
    __shared__ float rs[16], rs2[16], mv[2];
    for (int off = 32; off; off >>= 1) { s += __shfl_down(s, off); s2 += __shfl_down(s2, off); }
    int wid = threadIdx.x >> 6;
    if ((threadIdx.x & 63) == 0) { rs[wid] = s; rs2[wid] = s2; }
    __syncthreads();
    if (threadIdx.x == 0) {
        s = 0.f; s2 = 0.f;
#pragma unroll
        for (int k = 0; k < 16; ++k) { s += rs[k]; s2 += rs2[k]; }
        float m = s / (float)P;
        float var = s2 / (float)P - m * m;
        mv[0] = m; mv[1] = rsqrtf(var + 1e-5f);
    }
    __syncthreads();
    float m = mv[0], istd = mv[1];
    const float kS = 1.0507009873554805f, kA = 1.6732632423543772f;
    for (int i = threadIdx.x; i < 3456; i += 1024) {
        float4 v = src[i];
        float a0 = (v.x - m) * istd, a1 = (v.y - m) * istd;
        float a2 = (v.z - m) * istd, a3 = (v.w - m) * istd;
        v.x = a0 > 0.f ? kS * a0 : kS * kA * expm1f(a0);
        v.y = a1 > 0.f ? kS * a1 : kS * kA * expm1f(a1);
        v.z = a2 > 0.f ? kS * a2 : kS * kA * expm1f(a2);
        v.w = a3 > 0.f ? kS * a3 : kS * kA * expm1f(a3);
        src[i] = v;
    }
}

// ---------------- K6: in_proj via scalar-loaded activations (l-tile 24) ----------------
__global__ __launch_bounds__(192) void k_inproj(const float* __restrict__ Lx,
    const float* __restrict__ Wip, float* __restrict__ xi, float* __restrict__ z)
{
    int b = blockIdx.x / 576; int l0 = (blockIdx.x % 576) * 24;
    int e = threadIdx.x;   // 0..191
    float w[48];
#pragma unroll
    for (int c = 0; c < 48; ++c) w[c] = Wip[e*48 + c];
    float acc[24];
#pragma unroll
    for (int ll = 0; ll < 24; ++ll) acc[ll] = 0.f;
    const float* ub = Lx + (size_t)b * 48 * P + l0;   // wave-uniform
#pragma unroll 2
    for (int c = 0; c < 48; ++c) {
        const float* ur = ub + (size_t)c * P;          // uniform -> s_load
#pragma unroll
        for (int ll = 0; ll < 24; ++ll) acc[ll] = fmaf(w[c], ur[ll], acc[ll]);
    }
    float* dst = (e < 96) ? (xi + ((size_t)b * L + l0) * 96 + e)
                          : (z  + ((size_t)b * L + l0) * 96 + (e - 96));
#pragma unroll
    for (int ll = 0; ll < 24; ++ll) dst[(size_t)ll * 96] = acc[ll];
}

// ---------------- K7+K8 fused: conv1d+silu -> x_proj -> dt_proj+softplus (TL=32) ----------------
__global__ __launch_bounds__(256) void k_fxproj(const float* __restrict__ xi,
    const float* __restrict__ cw, const float* __restrict__ cb,
    const float* __restrict__ Wxp, const float* __restrict__ Wdt,
    const float* __restrict__ bdt, float* __restrict__ xs,
    float* __restrict__ delta, float* __restrict__ Bm, float* __restrict__ Cm)
{
    __shared__ float xs_t[TL][100];   // 12.8 KB, stride-100 pad
    __shared__ float wx_t[35][100];   // 14 KB
    __shared__ float wd_t[96][4];     // Wdt rows + bias packed
    __shared__ float dt_t[TL][4];
    int blk = blockIdx.x;             // 864 = NB * 432
    int b = blk / 432; int l0 = (blk % 432) * TL;
    int tid = threadIdx.x;

    for (int i = tid; i < 35 * 96; i += 256) wx_t[i / 96][i % 96] = Wxp[i];
    for (int i = tid; i < 96 * 3; i += 256) wd_t[i / 3][i % 3] = Wdt[i];
    for (int i = tid; i < 96; i += 256) wd_t[i][3] = bdt[i];

    int row = tid >> 3;               // 0..31
    int q8  = tid & 7;
    int d0  = q8 * 12;                // 12 d per thread
    int l = l0 + row;
    size_t t_glob = (size_t)b * L + l;
    const float* xib = xi + (size_t)b * L * 96;
    float* xsg = xs + t_glob * 96 + d0;
    int ls0 = l - 3;
    // ---- Phase B: conv1d + silu (3 float4 groups per thread) ----
#pragma unroll
    for (int jq = 0; jq < 3; ++jq) {
        int d = d0 + jq * 4;
        float4 t0 = *(const float4*)(cw + 4 * (d + 0));
        float4 t1 = *(const float4*)(cw + 4 * (d + 1));
        float4 t2 = *(const float4*)(cw + 4 * (d + 2));
        float4 t3 = *(const float4*)(cw + 4 * (d + 3));
        float4 acc = *(const float4*)(cb + d);
        float4 q0 = {0.f,0.f,0.f,0.f}, q1 = q0, q2 = q0;
        if (ls0 + 0 >= 0) q0 = *(const float4*)(xib + (size_t)(ls0 + 0) * 96 + d);
        if (ls0 + 1 >= 0) q1 = *(const float4*)(xib + (size_t)(ls0 + 1) * 96 + d);
        if (ls0 + 2 >= 0) q2 = *(const float4*)(xib + (size_t)(ls0 + 2) * 96 + d);
        float4 q3 = *(const float4*)(xib + (size_t)(ls0 + 3) * 96 + d);
        acc.x += t0.x*q0.x + t0.y*q1.x + t0.z*q2.x + t0.w*q3.x;
        acc.y += t1.x*q0.y + t1.y*q1.y + t1.z*q2.y + t1.w*q3.y;
        acc.z += t2.x*q0.z + t2.y*q1.z + t2.z*q2.z + t2.w*q3.z;
        acc.w += t3.x*q0.w + t3.y*q1.w + t3.z*q2.w + t3.w*q3.w;
        acc.x = siluf(acc.x); acc.y = siluf(acc.y);
        acc.z = siluf(acc.z); acc.w = siluf(acc.w);
        *(float4*)(&xs_t[row][d0 + jq * 4]) = acc;
        *(float4*)(xsg + jq * 4) = acc;
    }
    __syncthreads();

    // ---- Phase C: x_proj; thread (row, q8) computes e = q8 + 8k, k<5 ----
    float acc5[5];
#pragma unroll
    for (int k = 0; k < 5; ++k) acc5[k] = 0.f;
    const float* xrow = &xs_t[row][0];
#pragma unroll 4
    for (int j = 0; j < 24; ++j) {
        float4 xv = *(const float4*)(xrow + 4 * j);
#pragma unroll
        for (int k = 0; k < 5; ++k) {
            int e = q8 + 8 * k;
            if (e < 35) {
                float4 wv = *(const float4*)(&wx_t[e][4 * j]);
                acc5[k] = fmaf(wv.x, xv.x, fmaf(wv.y, xv.y,
                          fmaf(wv.z, xv.z, fmaf(wv.w, xv.w, acc5[k]))));
            }
        }
    }
#pragma unroll
    for (int k = 0; k < 5; ++k) {
        int e = q8 + 8 * k;
        if (e < 35) {
            if (e < 3)       dt_t[row][e] = acc5[k];
            else if (e < 19) Bm[t_glob * 16 + (e - 3)]  = acc5[k];
            else             Cm[t_glob * 16 + (e - 19)] = acc5[k];
        }
    }
    __syncthreads();

    // ---- Phase D: delta = softplus(Wdt . dt + bias), 12 d per thread ----
    float dt0 = dt_t[row][0], dt1 = dt_t[row][1], dt2 = dt_t[row][2];
    float* dl = delta + t_glob * 96 + d0;
#pragma unroll
    for (int jq = 0; jq < 3; ++jq) {
        float4 o;
        {
            float4 wv = *(const float4*)(&wd_t[d0 + jq*4 + 0][0]);
            o.x = softplusf(fmaf(wv.x, dt0, fmaf(wv.y, dt1, fmaf(wv.z, dt2, wv.w))));
        }
        {
            float4 wv = *(const float4*)(&wd_t[d0 + jq*4 + 1][0]);
            o.y = softplusf(fmaf(wv.x, dt0, fmaf(wv.y, dt1, fmaf(wv.z, dt2, wv.w))));
        }
        {
            float4 wv = *(const float4*)(&wd_t[d0 + jq*4 + 2][0]);
            o.z = softplusf(fmaf(wv.x, dt0, fmaf(wv.y, dt1, fmaf(wv.z, dt2, wv.w))));
        }
        {
            float4 wv = *(const float4*)(&wd_t[d0 + jq*4 + 3][0]);
            o.w = softplusf(fmaf(wv.x, dt0, fmaf(wv.y, dt1, fmaf(wv.z, dt2, wv.w))));
        }
        *(float4*)(dl + jq * 4) = o;
    }
}

// ---------------- K9: scan phase 1 — software-pipelined (CHUNK=64) ----------------
__global__ __launch_bounds__(256) void k_scan1(const float* __restrict__ delta,
    const float* __restrict__ xs, const float* __restrict__ Bm,
    const float* __restrict__ Alog, float* __restrict__ Aprod, float* __restrict__ hend)
{
    int wid = (blockIdx.x * 256 + threadIdx.x) >> 6;
    int lane = threadIdx.x & 63;
    int dg = wid % 24; int ch = (wid / 24) % NCK; int b = wid / (24 * NCK);
    int dl = lane >> 4, n = lane & 15;
    int d = dg * 4 + dl;
    float A = -__expf(Alog[d*16 + n]);
    float h = 0.f, ap = 1.f;
    int t0 = ch * CHUNK;
    const float* dp = delta + ((size_t)b * L + t0) * 96 + d;
    const float* xp = xs    + ((size_t)b * L + t0) * 96 + d;
    const float* bp = Bm    + ((size_t)b * L + t0) * 16 + n;

    float dA0, dA1, dA2, dA3, xA0, xA1, xA2, xA3, bA0, bA1, bA2, bA3;
    float dB0, dB1, dB2, dB3, xB0, xB1, xB2, xB3, bB0, bB1, bB2, bB3;
#define LD1(s, T) do { \
    d##s##0 = dp[(size_t)(T)*96];     x##s##0 = xp[(size_t)(T)*96];     b##s##0 = bp[(size_t)(T)*16]; \
    d##s##1 = dp[(size_t)((T)+1)*96]; x##s##1 = xp[(size_t)((T)+1)*96]; b##s##1 = bp[(size_t)((T)+1)*16]; \
    d##s##2 = dp[(size_t)((T)+2)*96]; x##s##2 = xp[(size_t)((T)+2)*96]; b##s##2 = bp[(size_t)((T)+2)*16]; \
    d##s##3 = dp[(size_t)((T)+3)*96]; x##s##3 = xp[(size_t)((T)+3)*96]; b##s##3 = bp[(size_t)((T)+3)*16]; \
  } while (0)
#define CMP1(s) do { \
    float e0 = __expf(d##s##0 * A); float e1 = __expf(d##s##1 * A); \
    float e2 = __expf(d##s##2 * A); float e3 = __expf(d##s##3 * A); \
    h = fmaf(e0, h, d##s##0 * x##s##0 * b##s##0); \
    h = fmaf(e1, h, d##s##1 * x##s##1 * b##s##1); \
    h = fmaf(e2, h, d##s##2 * x##s##2 * b##s##2); \
    h = fmaf(e3, h, d##s##3 * x##s##3 * b##s##3); \
    ap *= e0 * e1 * e2 * e3; \
  } while (0)

    LD1(A, 0);
#pragma unroll 1
    for (int t = 0; t < CHUNK; t += 8) {
        LD1(B, t + 4);
        CMP1(A);
        if (t + 8 < CHUNK) LD1(A, t + 8);
        CMP1(B);
    }
#undef LD1
#undef CMP1
    size_t idx = (((size_t)b * NCK + ch) * 96 + d) * 16 + n;
    Aprod[idx] = ap;
    hend[idx]  = h;
}

// ---------------- K10: scan phase 2 (NCK=216) ----------------
__global__ __launch_bounds__(256) void k_scan2(const float* __restrict__ Aprod,
    const float* __restrict__ hend, float* __restrict__ hin)
{
    int t = blockIdx.x * 256 + threadIdx.x;   // NB*1536 exact
    int b = t / 1536; int dn = t % 1536;
    const float* ap = Aprod + (size_t)b * NCK * 1536 + dn;
    const float* he = hend  + (size_t)b * NCK * 1536 + dn;
    float* hi       = hin   + (size_t)b * NCK * 1536 + dn;
    float carry = 0.f;
    float aA0, aA1, aA2, aA3, hA0, hA1, hA2, hA3;
    float aB0, aB1, aB2, aB3, hB0, hB1, hB2, hB3;
#define LD2(s, J) do { \
    a##s##0 = ap[(size_t)(J)*1536];     h##s##0 = he[(size_t)(J)*1536]; \
    a##s##1 = ap[(size_t)((J)+1)*1536]; h##s##1 = he[(size_t)((J)+1)*1536]; \
    a##s##2 = ap[(size_t)((J)+2)*1536]; h##s##2 = he[(size_t)((J)+2)*1536]; \
    a##s##3 = ap[(size_t)((J)+3)*1536]; h##s##3 = he[(size_t)((J)+3)*1536]; \
  } while (0)
#define CMP2(s, J) do { \
    hi[(size_t)(J)*1536]     = carry; carry = fmaf(a##s##0, carry, h##s##0); \
    hi[(size_t)((J)+1)*1536] = carry; carry = fmaf(a##s##1, carry, h##s##1); \
    hi[(size_t)((J)+2)*1536] = carry; carry = fmaf(a##s##2, carry, h##s##2); \
    hi[(size_t)((J)+3)*1536] = carry; carry = fmaf(a##s##3, carry, h##s##3); \
  } while (0)
    LD2(A, 0);
#pragma unroll 1
    for (int j = 0; j < NCK; j += 8) {
        LD2(B, j + 4);
        CMP2(A, j);
        if (j + 8 < NCK) LD2(A, j + 8);
        CMP2(B, j + 4);
    }
#undef LD2
#undef CMP2
}

// ---------------- K11: scan phase 3 — software-pipelined replay + y (CHUNK=64) ----------------
__global__ __launch_bounds__(256) void k_scan3(const float* __restrict__ delta,
    float* __restrict__ xs, const float* __restrict__ Bm, const float* __restrict__ Cm,
    const float* __restrict__ z, const float* __restrict__ Alog,
    const float* __restrict__ Dp, const float* __restrict__ hin)
{
    int wid = (blockIdx.x * 256 + threadIdx.x) >> 6;
    int lane = threadIdx.x & 63;
    int dg = wid % 24; int ch = (wid / 24) % NCK; int b = wid / (24 * NCK);
    int dl = lane >> 4, n = lane & 15;
    int d = dg * 4 + dl;
    float A = -__expf(Alog[d*16 + n]);
    float Dv = Dp[d];
    size_t cidx = (((size_t)b * NCK + ch) * 96 + d) * 16 + n;
    float h = hin[cidx];
    int t0 = ch * CHUNK;
    const float* dp = delta + ((size_t)b * L + t0) * 96 + d;
    float* xp       = xs    + ((size_t)b * L + t0) * 96 + d;
    const float* bp = Bm    + ((size_t)b * L + t0) * 16 + n;
    const float* cp = Cm    + ((size_t)b * L + t0) * 16 + n;
    const float* zp = z     + ((size_t)b * L + t0) * 96 + d;

    float dA0, dA1, dA2, dA3, xA0, xA1, xA2, xA3, bA0, bA1, bA2, bA3, cA0, cA1, cA2, cA3, zA0, zA1, zA2, zA3;
    float dB0, dB1, dB2, dB3, xB0, xB1, xB2, xB3, bB0, bB1, bB2, bB3, cB0, cB1, cB2, cB3, zB0, zB1, zB2, zB3;
#define LD3(s, T) do { \
    d##s##0 = dp[(size_t)(T)*96];     x##s##0 = xp[(size_t)(T)*96];     b##s##0 = bp[(size_t)(T)*16]; \
    c##s##0 = cp[(size_t)(T)*16];     z##s##0 = zp[(size_t)(T)*96]; \
    d##s##1 = dp[(size_t)((T)+1)*96]; x##s##1 = xp[(size_t)((T)+1)*96]; b##s##1 = bp[(size_t)((T)+1)*16]; \
    c##s##1 = cp[(size_t)((T)+1)*16]; z##s##1 = zp[(size_t)((T)+1)*96]; \
    d##s##2 = dp[(size_t)((T)+2)*96]; x##s##2 = xp[(size_t)((T)+2)*96]; b##s##2 = bp[(size_t)((T)+2)*16]; \
    c##s##2 = cp[(size_t)((T)+2)*16]; z##s##2 = zp[(size_t)((T)+2)*96]; \
    d##s##3 = dp[(size_t)((T)+3)*96]; x##s##3 = xp[(size_t)((T)+3)*96]; b##s##3 = bp[(size_t)((T)+3)*16]; \
    c##s##3 = cp[(size_t)((T)+3)*16]; z##s##3 = zp[(size_t)((T)+3)*96]; \
  } while (0)
#define STEP3(DEL, XV, BV, CV, ZV, T) do { \
    float dAv = __expf((DEL) * A); \
    h = fmaf(dAv, h, (DEL) * (XV) * (BV)); \
    float yc = h * (CV); \
    yc += __shfl_xor(yc, 8); \
    yc += __shfl_xor(yc, 4); \
    yc += __shfl_xor(yc, 2); \
    yc += __shfl_xor(yc, 1); \
    if (n == 0) xp[(size_t)(T)*96] = fmaf(Dv, (XV), yc) * siluf(ZV); \
  } while (0)
#define CMP3(s, T) do { \
    STEP3(d##s##0, x##s##0, b##s##0, c##s##0, z##s##0, (T)); \
    STEP3(d##s##1, x##s##1, b##s##1, c##s##1, z##s##1, (T)+1); \
    STEP3(d##s##2, x##s##2, b##s##2, c##s##2, z##s##2, (T)+2); \
    STEP3(d##s##3, x##s##3, b##s##3, c##s##3, z##s##3, (T)+3); \
  } while (0)

    LD3(A, 0);
#pragma unroll 1
    for (int t = 0; t < CHUNK; t += 8) {
        LD3(B, t + 4);
        CMP3(A, t);
        if (t + 8 < CHUNK) LD3(A, t + 8);
        CMP3(B, t + 4);
    }
#undef LD3
#undef STEP3
#undef CMP3
}

// ---------------- K12: out_proj + residual (oh-split x4) ----------------
__global__ __launch_bounds__(128) void k_outproj(const float* __restrict__ y,
    const float* __restrict__ Wopt, const float* __restrict__ Lx, float* __restrict__ out)
{
    int t = blockIdx.x * 128 + threadIdx.x;  // grid.x = 216
    int oh = blockIdx.y * 12;                // 0,12,24,36
    int b = t / P, p = t % P;
    const float* yr = y + (size_t)t * 96;
    float acc[12];
#pragma unroll
    for (int o = 0; o < 12; ++o) acc[o] = 0.f;
#pragma unroll
    for (int i = 0; i < 24; ++i) {
        float4 v4 = ((const float4*)yr)[i];
        const float* w0 = Wopt + (i*4) * 48 + oh;
        const float* w1 = Wopt + (i*4 + 1) * 48 + oh;
        const float* w2 = Wopt + (i*4 + 2) * 48 + oh;
        const float* w3 = Wopt + (i*4 + 3) * 48 + oh;
#pragma unroll
        for (int o = 0; o < 12; ++o) {
            acc[o] = fmaf(w0[o], v4.x, acc[o]);
            acc[o] = fmaf(w1[o], v4.y, acc[o]);
            acc[o] = fmaf(w2[o], v4.z, acc[o]);
            acc[o] = fmaf(w3[o], v4.w, acc[o]);
        }
    }
    const float* lx = Lx + (size_t)b * 48 * P + p;
    float* op = out + (size_t)b * 48 * P + p;
#pragma unroll
    for (int o = 0; o < 12; ++o) op[(size_t)(oh+o) * P] = acc[o] + lx[(size_t)(oh+o) * P];
}

extern "C" void kernel_launch(void* const* d_in, const int* in_sizes, int n_in,
                              void* d_out, int out_size, void* d_ws, size_t ws_size,
                              hipStream_t stream) {
    const float* x        = (const float*)d_in[0];
    const float* Hx       = (const float*)d_in[1];
    const float* W1       = (const float*)d_in[2];
    const float* b1       = (const float*)d_in[3];
    const float* W2       = (const float*)d_in[4];
    const float* b2       = (const float*)d_in[5];
    const float* W3       = (const float*)d_in[6];
    const float* b3       = (const float*)d_in[7];
    const float* in_proj  = (const float*)d_in[8];
    const float* conv1d_w = (const float*)d_in[9];
    const float* conv1d_b = (const float*)d_in[10];
    const float* x_proj   = (const float*)d_in[11];
    const float* dt_proj  = (const float*)d_in[12];
    const float* dt_bias  = (const float*)d_in[13];
    const float* A_log    = (const float*)d_in[14];
    const float* D_param  = (const float*)d_in[15];
    const float* out_proj = (const float*)d_in[16];
    float* out = (float*)d_out;

    float* ws = (float*)d_ws;
    const size_t SZ_BCP = (size_t)NB * 48 * P;      // 1,327,104
    const size_t SZ_BLD = (size_t)NB * L * 96;      // 2,654,208
    const size_t SZ_BLN = (size_t)NB * L * 16;      //   442,368
    const size_t SZ_CK  = (size_t)NB * NCK * 1536;  //   663,552 (CHUNK=64)
    float* bufA  = ws;                    // h1; later delta (spans bufA+bufB)
    float* bufB  = bufA + SZ_BCP;         // (free; part of delta)
    float* bufC  = bufB + SZ_BCP;         // h3 -> Lx (in place)
    float* xib   = bufC + SZ_BCP;         // xi; scan bufs overlay after fxproj
    float* zb    = xib  + SZ_BLD;         // z
    float* xsb   = zb   + SZ_BLD;         // xs, then y (in place)
    float* Bmb   = xsb  + SZ_BLD;
    float* Cmb   = Bmb  + SZ_BLN;
    float* stats = Cmb  + SZ_BLN;         // (unused; layout keep)
    float* Wtb   = stats + 192;           // 62,208 (W2 reshaped)
    float* W1tb  = Wtb + 62208;           // 6,912
    float* W3tb  = W1tb + 6912;           // 2,304
    float* Woptb = W3tb + 2304;           // 4,608
    float* deltab = bufA;                 // reuses h1 region (free after k_conv23)
    // scan intermediates overlay xi (dead after k_fxproj): 3*SZ_CK <= SZ_BLD
    float* Apr   = xib;
    float* hendb = xib + SZ_CK;
    float* hinb  = xib + 2 * SZ_CK;

    k_wtrans<<<297, 256, 0, stream>>>(W2, W1, W3, out_proj, Wtb, W1tb, W3tb, Woptb);
    k_conv1<<<dim3(216, 4), 128, 0, stream>>>(x, Hx, W1tb, b1, bufA);
    k_conv23<<<NB * 216, 512, 0, stream>>>(bufA, Wtb, b2, W3tb, b3, bufC);
    k_instnorm<<<NB * 48, 1024, 0, stream>>>(bufC);
    k_inproj<<<NB * 576, 192, 0, stream>>>(bufC, in_proj, xib, zb);
    k_fxproj<<<NB * 432, 256, 0, stream>>>(xib, conv1d_w, conv1d_b, x_proj, dt_proj,
                                           dt_bias, xsb, deltab, Bmb, Cmb);
    k_scan1<<<(NB * NCK * 24) / 4, 256, 0, stream>>>(deltab, xsb, Bmb, A_log, Apr, hendb);
    k_scan2<<<12, 256, 0, stream>>>(Apr, hendb, hinb);
    k_scan3<<<(NB * NCK * 24) / 4, 256, 0, stream>>>(deltab, xsb, Bmb, Cmb, zb, A_log,
                                                     D_param, hinb);
    k_outproj<<<dim3(216, 4), 128, 0, stream>>>(xsb, Woptb, bufC, out);
}

// Round 19
// 260.478 us; speedup vs baseline: 1.0590x; 1.0064x over previous
//
#include <hip/hip_runtime.h>
#include <math.h>

#define NB 2
#define NCH 48
#define P 13824        // 24^3
#define DI 96
#define NSTATE 16
#define L 13824
#define CHUNK 64
#define NCK 216        // L / CHUNK
#define TL 32          // rows per fused-xproj block

__device__ __forceinline__ float siluf(float x) { return x / (1.f + __expf(-x)); }
__device__ __forceinline__ float softplusf(float x) {
    return x > 0.f ? x + log1pf(expf(-x)) : log1pf(expf(x));
}

// ---------------- K0: weight reshuffles ----------------
// W2 [48o][48c][27t] -> Wt [4og][27t][48c][12oi]
__global__ __launch_bounds__(256) void k_wtrans(const float* __restrict__ W2,
    const float* __restrict__ W1, const float* __restrict__ W3,
    const float* __restrict__ Wop, float* __restrict__ Wt, float* __restrict__ W1t,
    float* __restrict__ W3t, float* __restrict__ Wopt)
{
    int i = blockIdx.x * 256 + threadIdx.x;
    if (i < 62208) {
        int o = i / (48 * 27); int r = i % (48 * 27); int c = r / 27; int tap = r % 27;
        int og = o / 12, oi = o % 12;
        Wt[(((og * 27 + tap) * 48 + c) * 12) + oi] = W2[i];
    } else if (i < 62208 + 6912) {
        int j = i - 62208; int o = j / 144, c = j % 144;
        W1t[c * 48 + o] = W1[j];
    } else if (i < 62208 + 6912 + 2304) {
        int j = i - 62208 - 6912; int o = j / 48, c = j % 48;
        W3t[c * 48 + o] = W3[j];
    } else if (i < 62208 + 6912 + 2304 + 4608) {
        int j = i - 62208 - 6912 - 2304; int o = j / 96, q = j % 96;
        Wopt[q * 48 + o] = Wop[j];
    }
}

// ---------------- K1: upsample + concat + 1x1x1 conv (oh-split x4) ----------------
__global__ __launch_bounds__(128) void k_conv1(const float* __restrict__ x,
    const float* __restrict__ Hx, const float* __restrict__ W1t,
    const float* __restrict__ b1, float* __restrict__ h1)
{
    int t = blockIdx.x * 128 + threadIdx.x;   // grid.x = 216
    int oh = blockIdx.y * 12;                 // 0,12,24,36
    int b = t / P, p = t % P;
    int zi = p / 576, yi = (p / 24) % 24, xi_ = p % 24;
    float fpos; int z0, z1, y0, y1, x0, x1; float wz, wy, wx;
    fpos = (float)(zi * 11) / 23.0f; z0 = (int)floorf(fpos); wz = fpos - z0; z1 = min(z0 + 1, 11);
    fpos = (float)(yi * 11) / 23.0f; y0 = (int)floorf(fpos); wy = fpos - y0; y1 = min(y0 + 1, 11);
    fpos = (float)(xi_ * 11) / 23.0f; x0 = (int)floorf(fpos); wx = fpos - x0; x1 = min(x0 + 1, 11);
    int o000 = (z0*12+y0)*12+x0, o001 = (z0*12+y0)*12+x1;
    int o010 = (z0*12+y1)*12+x0, o011 = (z0*12+y1)*12+x1;
    int o100 = (z1*12+y0)*12+x0, o101 = (z1*12+y0)*12+x1;
    int o110 = (z1*12+y1)*12+x0, o111 = (z1*12+y1)*12+x1;
    float uz = 1.f - wz, uy = 1.f - wy, ux = 1.f - wx;
    float w000 = uz*uy*ux, w001 = uz*uy*wx, w010 = uz*wy*ux, w011 = uz*wy*wx;
    float w100 = wz*uy*ux, w101 = wz*uy*wx, w110 = wz*wy*ux, w111 = wz*wy*wx;

    float acc[12];
#pragma unroll
    for (int o = 0; o < 12; ++o) acc[o] = b1[oh + o];
    const float* xb = x + (size_t)b * 48 * 1728;
    for (int c0 = 0; c0 < 48; c0 += 4) {
        float a[4][8];
#pragma unroll
        for (int j = 0; j < 4; ++j) {
            const float* xc = xb + (c0 + j) * 1728;
            a[j][0] = xc[o000]; a[j][1] = xc[o001]; a[j][2] = xc[o010]; a[j][3] = xc[o011];
            a[j][4] = xc[o100]; a[j][5] = xc[o101]; a[j][6] = xc[o110]; a[j][7] = xc[o111];
        }
#pragma unroll
        for (int j = 0; j < 4; ++j) {
            float v = a[j][0]*w000 + a[j][1]*w001 + a[j][2]*w010 + a[j][3]*w011
                    + a[j][4]*w100 + a[j][5]*w101 + a[j][6]*w110 + a[j][7]*w111;
            const float* wr = W1t + (c0 + j) * 48 + oh;
#pragma unroll
            for (int o = 0; o < 12; ++o) acc[o] = fmaf(wr[o], v, acc[o]);
        }
    }
    const float* hb = Hx + (size_t)b * 96 * P + p;
    for (int c0 = 0; c0 < 96; c0 += 8) {
        float v[8];
#pragma unroll
        for (int j = 0; j < 8; ++j) v[j] = hb[(size_t)(c0 + j) * P];
#pragma unroll
        for (int j = 0; j < 8; ++j) {
            const float* wr = W1t + (48 + c0 + j) * 48 + oh;
#pragma unroll
            for (int o = 0; o < 12; ++o) acc[o] = fmaf(wr[o], v[j], acc[o]);
        }
    }
    float* out = h1 + (size_t)b * 48 * P + p;
#pragma unroll
    for (int o = 0; o < 12; ++o) out[(size_t)(oh+o) * P] = acc[o];
}

// ---------------- K2: fused 3x3x3 + 1x1x1 conv; dual-partial epilogue (3 syncs) ----------------
__global__ __launch_bounds__(512) void k_conv23(const float* __restrict__ h1,
    const float* __restrict__ Wt, const float* __restrict__ b2,
    const float* __restrict__ W3t, const float* __restrict__ b3,
    float* __restrict__ h3)
{
    __shared__ float tile[216 * 52];   // 43.9 KB; reused post-compute: part[2][48][64] = 24 KB
    int blk = blockIdx.x;              // b*216 + tz*36 + ty*6 + tx
    int b = blk / 216; int r = blk % 216;
    int tz = r / 36, ty = (r / 6) % 6, tx = r % 6;
    int z0 = tz*4 - 1, y0 = ty*4 - 1, x0 = tx*4 - 1;
    // staging: thread = (q, c4); 4 coalesced loads + 1 ds_write_b128 (conflict-free)
    for (int i = threadIdx.x; i < 216 * 12; i += 512) {
        int q = i % 216; int c4 = (i / 216) * 4;
        int lz = q / 36, ly = (q / 6) % 6, lx = q % 6;
        int gz = z0 + lz, gy = y0 + ly, gx = x0 + lx;
        float4 v = {0.f, 0.f, 0.f, 0.f};
        if ((unsigned)gz < 24u && (unsigned)gy < 24u && (unsigned)gx < 24u) {
            size_t gp = (size_t)(gz*24 + gy)*24 + gx;
            const float* hp = h1 + ((size_t)(b*48 + c4)) * P + gp;
            v.x = hp[0];
            v.y = hp[P];
            v.z = hp[2*P];
            v.w = hp[3*P];
        }
        *(float4*)(&tile[q*52 + c4]) = v;
    }
    __syncthreads();
    int lp = threadIdx.x & 63;
    int w  = __builtin_amdgcn_readfirstlane((int)(threadIdx.x >> 6));  // 0..7 SGPR
    int og = w & 3, cc = w >> 2;
    int lz = lp >> 4, ly = (lp >> 2) & 3, lx = lp & 3;
    float acc[12];
#pragma unroll
    for (int i = 0; i < 12; ++i) acc[i] = cc ? 0.f : b2[og*12 + i];
#pragma unroll
    for (int dz = 0; dz < 3; ++dz)
#pragma unroll
    for (int dy = 0; dy < 3; ++dy)
#pragma unroll
    for (int dx = 0; dx < 3; ++dx) {
        int pos = (lz+dz)*36 + (ly+dy)*6 + (lx+dx);
        const float* tp = tile + pos*52 + cc*24;
        int tap = (dz*3 + dy)*3 + dx;
        const float* wt = Wt + (((size_t)og*27 + tap)*48 + cc*24)*12;  // uniform -> s_load
#pragma unroll
        for (int cq = 0; cq < 6; ++cq) {
            float4 v4 = *(const float4*)(tp + cq*4);     // ds_read_b128, bank-uniform
            const float* wq = wt + cq*48;
#pragma unroll
            for (int i = 0; i < 12; ++i) {
                acc[i] = fmaf(wq[i],      v4.x, acc[i]);
                acc[i] = fmaf(wq[12 + i], v4.y, acc[i]);
                acc[i] = fmaf(wq[24 + i], v4.z, acc[i]);
                acc[i] = fmaf(wq[36 + i], v4.w, acc[i]);
            }
        }
    }
    __syncthreads();                   // tile reads complete; reuse tile
    // both halves write partials: part[cc][og*12+i][64] — all 8 waves active, conflict-free
    {
        float* pt = tile + cc * 3072 + og * 768;
#pragma unroll
        for (int i = 0; i < 12; ++i) pt[i*64 + lp] = acc[i];
    }
    __syncthreads();
    // ---- conv3 (1x1x1, 48->48): wave w handles 6 outputs; sums both partials inline ----
    const float* htA = tile;           // cc=0 partials [48][64] (includes b2)
    const float* htB = tile + 3072;    // cc=1 partials [48][64]
    int oc0 = w * 6;
    float acc3[6];
#pragma unroll
    for (int j = 0; j < 6; ++j) acc3[j] = b3[oc0 + j];        // uniform -> s_load
    for (int c = 0; c < 48; ++c) {
        float v = htA[c*64 + lp] + htB[c*64 + lp];            // conflict-free
        const float* wr = W3t + c*48 + oc0;                   // uniform -> s_load
#pragma unroll
        for (int j = 0; j < 6; ++j) acc3[j] = fmaf(wr[j], v, acc3[j]);
    }
    int gz = tz*4 + lz, gy = ty*4 + ly, gx = tx*4 + lx;
    size_t pp = (size_t)(gz*24 + gy)*24 + gx;
#pragma unroll
    for (int j = 0; j < 6; ++j)
        h3[((size_t)(b*48) + oc0 + j) * P + pp] = acc3[j];
}

// ---------------- K4: fused instance-norm stats + normalize + SELU (1024 thr) ----------------
__global__ __launch_bounds__(1024) void k_instnorm(float* __restrict__ h3)
{
    int bc = blockIdx.x;   // 0..95
    float4* src = (float4*)(h3 + (size_t)bc * P);   // 3456 float4
    float s = 0.f, s2 = 0.f;
    for (int i = threadIdx.x; i < 3456; i += 1024) {
        float4 v = src[i];
        s  += v.x + v.y + v.z + v.w;
        s2 += v.x*v.x + v.y*v.y + v.z*v.z + v.w*v.w;
    }
    __shared__ float rs[16], rs2[16], mv[2];
    for (int off = 32; off; off >>= 1) { s += __shfl_down(s, off); s2 += __shfl_down(s2, off); }
    int wid = threadIdx.x >> 6;
    if ((threadIdx.x & 63) == 0) { rs[wid] = s; rs2[wid] = s2; }
    __syncthreads();
    if (threadIdx.x == 0) {
        s = 0.f; s2 = 0.f;
#pragma unroll
        for (int k = 0; k < 16; ++k) { s += rs[k]; s2 += rs2[k]; }
        float m = s / (float)P;
        float var = s2 / (float)P - m * m;
        mv[0] = m; mv[1] = rsqrtf(var + 1e-5f);
    }
    __syncthreads();
    float m = mv[0], istd = mv[1];
    const float kS = 1.0507009873554805f, kA = 1.6732632423543772f;
    for (int i = threadIdx.x; i < 3456; i += 1024) {
        float4 v = src[i];
        float a0 = (v.x - m) * istd, a1 = (v.y - m) * istd;
        float a2 = (v.z - m) * istd, a3 = (v.w - m) * istd;
        v.x = a0 > 0.f ? kS * a0 : kS * kA * expm1f(a0);
        v.y = a1 > 0.f ? kS * a1 : kS * kA * expm1f(a1);
        v.z = a2 > 0.f ? kS * a2 : kS * kA * expm1f(a2);
        v.w = a3 > 0.f ? kS * a3 : kS * kA * expm1f(a3);
        src[i] = v;
    }
}

// ---------------- K6: in_proj via scalar-loaded activations (l-tile 24) ----------------
__global__ __launch_bounds__(192) void k_inproj(const float* __restrict__ Lx,
    const float* __restrict__ Wip, float* __restrict__ xi, float* __restrict__ z)
{
    int b = blockIdx.x / 576; int l0 = (blockIdx.x % 576) * 24;
    int e = threadIdx.x;   // 0..191
    float w[48];
#pragma unroll
    for (int c = 0; c < 48; ++c) w[c] = Wip[e*48 + c];
    float acc[24];
#pragma unroll
    for (int ll = 0; ll < 24; ++ll) acc[ll] = 0.f;
    const float* ub = Lx + (size_t)b * 48 * P + l0;   // wave-uniform
#pragma unroll 2
    for (int c = 0; c < 48; ++c) {
        const float* ur = ub + (size_t)c * P;          // uniform -> s_load
#pragma unroll
        for (int ll = 0; ll < 24; ++ll) acc[ll] = fmaf(w[c], ur[ll], acc[ll]);
    }
    float* dst = (e < 96) ? (xi + ((size_t)b * L + l0) * 96 + e)
                          : (z  + ((size_t)b * L + l0) * 96 + (e - 96));
#pragma unroll
    for (int ll = 0; ll < 24; ++ll) dst[(size_t)ll * 96] = acc[ll];
}

// ---------------- K7+K8 fused: conv1d+silu -> x_proj -> dt_proj+softplus (TL=32) ----------------
__global__ __launch_bounds__(256) void k_fxproj(const float* __restrict__ xi,
    const float* __restrict__ cw, const float* __restrict__ cb,
    const float* __restrict__ Wxp, const float* __restrict__ Wdt,
    const float* __restrict__ bdt, float* __restrict__ xs,
    float* __restrict__ delta, float* __restrict__ Bm, float* __restrict__ Cm)
{
    __shared__ float xs_t[TL][100];   // 12.8 KB, stride-100 pad
    __shared__ float wx_t[35][100];   // 14 KB
    __shared__ float wd_t[96][4];     // Wdt rows + bias packed
    __shared__ float dt_t[TL][4];
    int blk = blockIdx.x;             // 864 = NB * 432
    int b = blk / 432; int l0 = (blk % 432) * TL;
    int tid = threadIdx.x;

    for (int i = tid; i < 35 * 96; i += 256) wx_t[i / 96][i % 96] = Wxp[i];
    for (int i = tid; i < 96 * 3; i += 256) wd_t[i / 3][i % 3] = Wdt[i];
    for (int i = tid; i < 96; i += 256) wd_t[i][3] = bdt[i];

    int row = tid >> 3;               // 0..31
    int q8  = tid & 7;
    int d0  = q8 * 12;                // 12 d per thread
    int l = l0 + row;
    size_t t_glob = (size_t)b * L + l;
    const float* xib = xi + (size_t)b * L * 96;
    float* xsg = xs + t_glob * 96 + d0;
    int ls0 = l - 3;
    // ---- Phase B: conv1d + silu (3 float4 groups per thread) ----
#pragma unroll
    for (int jq = 0; jq < 3; ++jq) {
        int d = d0 + jq * 4;
        float4 t0 = *(const float4*)(cw + 4 * (d + 0));
        float4 t1 = *(const float4*)(cw + 4 * (d + 1));
        float4 t2 = *(const float4*)(cw + 4 * (d + 2));
        float4 t3 = *(const float4*)(cw + 4 * (d + 3));
        float4 acc = *(const float4*)(cb + d);
        float4 q0 = {0.f,0.f,0.f,0.f}, q1 = q0, q2 = q0;
        if (ls0 + 0 >= 0) q0 = *(const float4*)(xib + (size_t)(ls0 + 0) * 96 + d);
        if (ls0 + 1 >= 0) q1 = *(const float4*)(xib + (size_t)(ls0 + 1) * 96 + d);
        if (ls0 + 2 >= 0) q2 = *(const float4*)(xib + (size_t)(ls0 + 2) * 96 + d);
        float4 q3 = *(const float4*)(xib + (size_t)(ls0 + 3) * 96 + d);
        acc.x += t0.x*q0.x + t0.y*q1.x + t0.z*q2.x + t0.w*q3.x;
        acc.y += t1.x*q0.y + t1.y*q1.y + t1.z*q2.y + t1.w*q3.y;
        acc.z += t2.x*q0.z + t2.y*q1.z + t2.z*q2.z + t2.w*q3.z;
        acc.w += t3.x*q0.w + t3.y*q1.w + t3.z*q2.w + t3.w*q3.w;
        acc.x = siluf(acc.x); acc.y = siluf(acc.y);
        acc.z = siluf(acc.z); acc.w = siluf(acc.w);
        *(float4*)(&xs_t[row][d0 + jq * 4]) = acc;
        *(float4*)(xsg + jq * 4) = acc;
    }
    __syncthreads();

    // ---- Phase C: x_proj; thread (row, q8) computes e = q8 + 8k, k<5 ----
    float acc5[5];
#pragma unroll
    for (int k = 0; k < 5; ++k) acc5[k] = 0.f;
    const float* xrow = &xs_t[row][0];
#pragma unroll 4
    for (int j = 0; j < 24; ++j) {
        float4 xv = *(const float4*)(xrow + 4 * j);
#pragma unroll
        for (int k = 0; k < 5; ++k) {
            int e = q8 + 8 * k;
            if (e < 35) {
                float4 wv = *(const float4*)(&wx_t[e][4 * j]);
                acc5[k] = fmaf(wv.x, xv.x, fmaf(wv.y, xv.y,
                          fmaf(wv.z, xv.z, fmaf(wv.w, xv.w, acc5[k]))));
            }
        }
    }
#pragma unroll
    for (int k = 0; k < 5; ++k) {
        int e = q8 + 8 * k;
        if (e < 35) {
            if (e < 3)       dt_t[row][e] = acc5[k];
            else if (e < 19) Bm[t_glob * 16 + (e - 3)]  = acc5[k];
            else             Cm[t_glob * 16 + (e - 19)] = acc5[k];
        }
    }
    __syncthreads();

    // ---- Phase D: delta = softplus(Wdt . dt + bias), 12 d per thread ----
    float dt0 = dt_t[row][0], dt1 = dt_t[row][1], dt2 = dt_t[row][2];
    float* dl = delta + t_glob * 96 + d0;
#pragma unroll
    for (int jq = 0; jq < 3; ++jq) {
        float4 o;
        {
            float4 wv = *(const float4*)(&wd_t[d0 + jq*4 + 0][0]);
            o.x = softplusf(fmaf(wv.x, dt0, fmaf(wv.y, dt1, fmaf(wv.z, dt2, wv.w))));
        }
        {
            float4 wv = *(const float4*)(&wd_t[d0 + jq*4 + 1][0]);
            o.y = softplusf(fmaf(wv.x, dt0, fmaf(wv.y, dt1, fmaf(wv.z, dt2, wv.w))));
        }
        {
            float4 wv = *(const float4*)(&wd_t[d0 + jq*4 + 2][0]);
            o.z = softplusf(fmaf(wv.x, dt0, fmaf(wv.y, dt1, fmaf(wv.z, dt2, wv.w))));
        }
        {
            float4 wv = *(const float4*)(&wd_t[d0 + jq*4 + 3][0]);
            o.w = softplusf(fmaf(wv.x, dt0, fmaf(wv.y, dt1, fmaf(wv.z, dt2, wv.w))));
        }
        *(float4*)(dl + jq * 4) = o;
    }
}

// ---------------- K9: scan phase 1 — software-pipelined (CHUNK=64) ----------------
__global__ __launch_bounds__(256) void k_scan1(const float* __restrict__ delta,
    const float* __restrict__ xs, const float* __restrict__ Bm,
    const float* __restrict__ Alog, float* __restrict__ Aprod, float* __restrict__ hend)
{
    int wid = (blockIdx.x * 256 + threadIdx.x) >> 6;
    int lane = threadIdx.x & 63;
    int dg = wid % 24; int ch = (wid / 24) % NCK; int b = wid / (24 * NCK);
    int dl = lane >> 4, n = lane & 15;
    int d = dg * 4 + dl;
    float A = -__expf(Alog[d*16 + n]);
    float h = 0.f, ap = 1.f;
    int t0 = ch * CHUNK;
    const float* dp = delta + ((size_t)b * L + t0) * 96 + d;
    const float* xp = xs    + ((size_t)b * L + t0) * 96 + d;
    const float* bp = Bm    + ((size_t)b * L + t0) * 16 + n;

    float dA0, dA1, dA2, dA3, xA0, xA1, xA2, xA3, bA0, bA1, bA2, bA3;
    float dB0, dB1, dB2, dB3, xB0, xB1, xB2, xB3, bB0, bB1, bB2, bB3;
#define LD1(s, T) do { \
    d##s##0 = dp[(size_t)(T)*96];     x##s##0 = xp[(size_t)(T)*96];     b##s##0 = bp[(size_t)(T)*16]; \
    d##s##1 = dp[(size_t)((T)+1)*96]; x##s##1 = xp[(size_t)((T)+1)*96]; b##s##1 = bp[(size_t)((T)+1)*16]; \
    d##s##2 = dp[(size_t)((T)+2)*96]; x##s##2 = xp[(size_t)((T)+2)*96]; b##s##2 = bp[(size_t)((T)+2)*16]; \
    d##s##3 = dp[(size_t)((T)+3)*96]; x##s##3 = xp[(size_t)((T)+3)*96]; b##s##3 = bp[(size_t)((T)+3)*16]; \
  } while (0)
#define CMP1(s) do { \
    float e0 = __expf(d##s##0 * A); float e1 = __expf(d##s##1 * A); \
    float e2 = __expf(d##s##2 * A); float e3 = __expf(d##s##3 * A); \
    h = fmaf(e0, h, d##s##0 * x##s##0 * b##s##0); \
    h = fmaf(e1, h, d##s##1 * x##s##1 * b##s##1); \
    h = fmaf(e2, h, d##s##2 * x##s##2 * b##s##2); \
    h = fmaf(e3, h, d##s##3 * x##s##3 * b##s##3); \
    ap *= e0 * e1 * e2 * e3; \
  } while (0)

    LD1(A, 0);
#pragma unroll 1
    for (int t = 0; t < CHUNK; t += 8) {
        LD1(B, t + 4);
        CMP1(A);
        if (t + 8 < CHUNK) LD1(A, t + 8);
        CMP1(B);
    }
#undef LD1
#undef CMP1
    size_t idx = (((size_t)b * NCK + ch) * 96 + d) * 16 + n;
    Aprod[idx] = ap;
    hend[idx]  = h;
}

// ---------------- K10: scan phase 2 (NCK=216) ----------------
__global__ __launch_bounds__(256) void k_scan2(const float* __restrict__ Aprod,
    const float* __restrict__ hend, float* __restrict__ hin)
{
    int t = blockIdx.x * 256 + threadIdx.x;   // NB*1536 exact
    int b = t / 1536; int dn = t % 1536;
    const float* ap = Aprod + (size_t)b * NCK * 1536 + dn;
    const float* he = hend  + (size_t)b * NCK * 1536 + dn;
    float* hi       = hin   + (size_t)b * NCK * 1536 + dn;
    float carry = 0.f;
    float aA0, aA1, aA2, aA3, hA0, hA1, hA2, hA3;
    float aB0, aB1, aB2, aB3, hB0, hB1, hB2, hB3;
#define LD2(s, J) do { \
    a##s##0 = ap[(size_t)(J)*1536];     h##s##0 = he[(size_t)(J)*1536]; \
    a##s##1 = ap[(size_t)((J)+1)*1536]; h##s##1 = he[(size_t)((J)+1)*1536]; \
    a##s##2 = ap[(size_t)((J)+2)*1536]; h##s##2 = he[(size_t)((J)+2)*1536]; \
    a##s##3 = ap[(size_t)((J)+3)*1536]; h##s##3 = he[(size_t)((J)+3)*1536]; \
  } while (0)
#define CMP2(s, J) do { \
    hi[(size_t)(J)*1536]     = carry; carry = fmaf(a##s##0, carry, h##s##0); \
    hi[(size_t)((J)+1)*1536] = carry; carry = fmaf(a##s##1, carry, h##s##1); \
    hi[(size_t)((J)+2)*1536] = carry; carry = fmaf(a##s##2, carry, h##s##2); \
    hi[(size_t)((J)+3)*1536] = carry; carry = fmaf(a##s##3, carry, h##s##3); \
  } while (0)
    LD2(A, 0);
#pragma unroll 1
    for (int j = 0; j < NCK; j += 8) {
        LD2(B, j + 4);
        CMP2(A, j);
        if (j + 8 < NCK) LD2(A, j + 8);
        CMP2(B, j + 4);
    }
#undef LD2
#undef CMP2
}

// ---------------- K11: scan phase 3 — software-pipelined replay + y (CHUNK=64) ----------------
__global__ __launch_bounds__(256) void k_scan3(const float* __restrict__ delta,
    float* __restrict__ xs, const float* __restrict__ Bm, const float* __restrict__ Cm,
    const float* __restrict__ z, const float* __restrict__ Alog,
    const float* __restrict__ Dp, const float* __restrict__ hin)
{
    int wid = (blockIdx.x * 256 + threadIdx.x) >> 6;
    int lane = threadIdx.x & 63;
    int dg = wid % 24; int ch = (wid / 24) % NCK; int b = wid / (24 * NCK);
    int dl = lane >> 4, n = lane & 15;
    int d = dg * 4 + dl;
    float A = -__expf(Alog[d*16 + n]);
    float Dv = Dp[d];
    size_t cidx = (((size_t)b * NCK + ch) * 96 + d) * 16 + n;
    float h = hin[cidx];
    int t0 = ch * CHUNK;
    const float* dp = delta + ((size_t)b * L + t0) * 96 + d;
    float* xp       = xs    + ((size_t)b * L + t0) * 96 + d;
    const float* bp = Bm    + ((size_t)b * L + t0) * 16 + n;
    const float* cp = Cm    + ((size_t)b * L + t0) * 16 + n;
    const float* zp = z     + ((size_t)b * L + t0) * 96 + d;

    float dA0, dA1, dA2, dA3, xA0, xA1, xA2, xA3, bA0, bA1, bA2, bA3, cA0, cA1, cA2, cA3, zA0, zA1, zA2, zA3;
    float dB0, dB1, dB2, dB3, xB0, xB1, xB2, xB3, bB0, bB1, bB2, bB3, cB0, cB1, cB2, cB3, zB0, zB1, zB2, zB3;
#define LD3(s, T) do { \
    d##s##0 = dp[(size_t)(T)*96];     x##s##0 = xp[(size_t)(T)*96];     b##s##0 = bp[(size_t)(T)*16]; \
    c##s##0 = cp[(size_t)(T)*16];     z##s##0 = zp[(size_t)(T)*96]; \
    d##s##1 = dp[(size_t)((T)+1)*96]; x##s##1 = xp[(size_t)((T)+1)*96]; b##s##1 = bp[(size_t)((T)+1)*16]; \
    c##s##1 = cp[(size_t)((T)+1)*16]; z##s##1 = zp[(size_t)((T)+1)*96]; \
    d##s##2 = dp[(size_t)((T)+2)*96]; x##s##2 = xp[(size_t)((T)+2)*96]; b##s##2 = bp[(size_t)((T)+2)*16]; \
    c##s##2 = cp[(size_t)((T)+2)*16]; z##s##2 = zp[(size_t)((T)+2)*96]; \
    d##s##3 = dp[(size_t)((T)+3)*96]; x##s##3 = xp[(size_t)((T)+3)*96]; b##s##3 = bp[(size_t)((T)+3)*16]; \
    c##s##3 = cp[(size_t)((T)+3)*16]; z##s##3 = zp[(size_t)((T)+3)*96]; \
  } while (0)
#define STEP3(DEL, XV, BV, CV, ZV, T) do { \
    float dAv = __expf((DEL) * A); \
    h = fmaf(dAv, h, (DEL) * (XV) * (BV)); \
    float yc = h * (CV); \
    yc += __shfl_xor(yc, 8); \
    yc += __shfl_xor(yc, 4); \
    yc += __shfl_xor(yc, 2); \
    yc += __shfl_xor(yc, 1); \
    if (n == 0) xp[(size_t)(T)*96] = fmaf(Dv, (XV), yc) * siluf(ZV); \
  } while (0)
#define CMP3(s, T) do { \
    STEP3(d##s##0, x##s##0, b##s##0, c##s##0, z##s##0, (T)); \
    STEP3(d##s##1, x##s##1, b##s##1, c##s##1, z##s##1, (T)+1); \
    STEP3(d##s##2, x##s##2, b##s##2, c##s##2, z##s##2, (T)+2); \
    STEP3(d##s##3, x##s##3, b##s##3, c##s##3, z##s##3, (T)+3); \
  } while (0)

    LD3(A, 0);
#pragma unroll 1
    for (int t = 0; t < CHUNK; t += 8) {
        LD3(B, t + 4);
        CMP3(A, t);
        if (t + 8 < CHUNK) LD3(A, t + 8);
        CMP3(B, t + 4);
    }
#undef LD3
#undef STEP3
#undef CMP3
}

// ---------------- K12: out_proj + residual (oh-split x4) ----------------
__global__ __launch_bounds__(128) void k_outproj(const float* __restrict__ y,
    const float* __restrict__ Wopt, const float* __restrict__ Lx, float* __restrict__ out)
{
    int t = blockIdx.x * 128 + threadIdx.x;  // grid.x = 216
    int oh = blockIdx.y * 12;                // 0,12,24,36
    int b = t / P, p = t % P;
    const float* yr = y + (size_t)t * 96;
    float acc[12];
#pragma unroll
    for (int o = 0; o < 12; ++o) acc[o] = 0.f;
#pragma unroll
    for (int i = 0; i < 24; ++i) {
        float4 v4 = ((const float4*)yr)[i];
        const float* w0 = Wopt + (i*4) * 48 + oh;
        const float* w1 = Wopt + (i*4 + 1) * 48 + oh;
        const float* w2 = Wopt + (i*4 + 2) * 48 + oh;
        const float* w3 = Wopt + (i*4 + 3) * 48 + oh;
#pragma unroll
        for (int o = 0; o < 12; ++o) {
            acc[o] = fmaf(w0[o], v4.x, acc[o]);
            acc[o] = fmaf(w1[o], v4.y, acc[o]);
            acc[o] = fmaf(w2[o], v4.z, acc[o]);
            acc[o] = fmaf(w3[o], v4.w, acc[o]);
        }
    }
    const float* lx = Lx + (size_t)b * 48 * P + p;
    float* op = out + (size_t)b * 48 * P + p;
#pragma unroll
    for (int o = 0; o < 12; ++o) op[(size_t)(oh+o) * P] = acc[o] + lx[(size_t)(oh+o) * P];
}

extern "C" void kernel_launch(void* const* d_in, const int* in_sizes, int n_in,
                              void* d_out, int out_size, void* d_ws, size_t ws_size,
                              hipStream_t stream) {
    const float* x        = (const float*)d_in[0];
    const float* Hx       = (const float*)d_in[1];
    const float* W1       = (const float*)d_in[2];
    const float* b1       = (const float*)d_in[3];
    const float* W2       = (const float*)d_in[4];
    const float* b2       = (const float*)d_in[5];
    const float* W3       = (const float*)d_in[6];
    const float* b3       = (const float*)d_in[7];
    const float* in_proj  = (const float*)d_in[8];
    const float* conv1d_w = (const float*)d_in[9];
    const float* conv1d_b = (const float*)d_in[10];
    const float* x_proj   = (const float*)d_in[11];
    const float* dt_proj  = (const float*)d_in[12];
    const float* dt_bias  = (const float*)d_in[13];
    const float* A_log    = (const float*)d_in[14];
    const float* D_param  = (const float*)d_in[15];
    const float* out_proj = (const float*)d_in[16];
    float* out = (float*)d_out;

    float* ws = (float*)d_ws;
    const size_t SZ_BCP = (size_t)NB * 48 * P;      // 1,327,104
    const size_t SZ_BLD = (size_t)NB * L * 96;      // 2,654,208
    const size_t SZ_BLN = (size_t)NB * L * 16;      //   442,368
    const size_t SZ_CK  = (size_t)NB * NCK * 1536;  //   663,552 (CHUNK=64)
    float* bufA  = ws;                    // h1; later delta (spans bufA+bufB)
    float* bufB  = bufA + SZ_BCP;         // (free; part of delta)
    float* bufC  = bufB + SZ_BCP;         // h3 -> Lx (in place)
    float* xib   = bufC + SZ_BCP;         // xi; scan bufs overlay after fxproj
    float* zb    = xib  + SZ_BLD;         // z
    float* xsb   = zb   + SZ_BLD;         // xs, then y (in place)
    float* Bmb   = xsb  + SZ_BLD;
    float* Cmb   = Bmb  + SZ_BLN;
    float* stats = Cmb  + SZ_BLN;         // (unused; layout keep)
    float* Wtb   = stats + 192;           // 62,208 (W2 reshaped)
    float* W1tb  = Wtb + 62208;           // 6,912
    float* W3tb  = W1tb + 6912;           // 2,304
    float* Woptb = W3tb + 2304;           // 4,608
    float* deltab = bufA;                 // reuses h1 region (free after k_conv23)
    // scan intermediates overlay xi (dead after k_fxproj): 3*SZ_CK <= SZ_BLD
    float* Apr   = xib;
    float* hendb = xib + SZ_CK;
    float* hinb  = xib + 2 * SZ_CK;

    k_wtrans<<<297, 256, 0, stream>>>(W2, W1, W3, out_proj, Wtb, W1tb, W3tb, Woptb);
    k_conv1<<<dim3(216, 4), 128, 0, stream>>>(x, Hx, W1tb, b1, bufA);
    k_conv23<<<NB * 216, 512, 0, stream>>>(bufA, Wtb, b2, W3tb, b3, bufC);
    k_instnorm<<<NB * 48, 1024, 0, stream>>>(bufC);
    k_inproj<<<NB * 576, 192, 0, stream>>>(bufC, in_proj, xib, zb);
    k_fxproj<<<NB * 432, 256, 0, stream>>>(xib, conv1d_w, conv1d_b, x_proj, dt_proj,
                                           dt_bias, xsb, deltab, Bmb, Cmb);
    k_scan1<<<(NB * NCK * 24) / 4, 256, 0, stream>>>(deltab, xsb, Bmb, A_log, Apr, hendb);
    k_scan2<<<12, 256, 0, stream>>>(Apr, hendb, hinb);
    k_scan3<<<(NB * NCK * 24) / 4, 256, 0, stream>>>(deltab, xsb, Bmb, Cmb, zb, A_log,
                                                     D_param, hinb);
    k_outproj<<<dim3(216, 4), 128, 0, stream>>>(xsb, Woptb, bufC, out);
}